// Round 4
// baseline (3933.921 us; speedup 1.0000x reference)
//
#include <hip/hip_runtime.h>
#include <math.h>

#define NS 1000
#define NQ 131072
#define D  1024
#define C  100
#define CP 112          // padded class count (16*7)
#define BETA 5.0f
#define NITER 10
#define KC2 128         // split-K chunks for W^T q
#define KROWS (NQ/KC2)  // 1024 q per chunk -> 32 k-steps of 32

typedef float f32x4 __attribute__((ext_vector_type(4)));
typedef short s16x8 __attribute__((ext_vector_type(8)));
typedef unsigned short u16;

__device__ __forceinline__ u16 f2bf(float x) {
  union { float f; unsigned u; } v; v.f = x;
  unsigned r = v.u + 0x7fffu + ((v.u >> 16) & 1u);
  return (u16)(r >> 16);
}
__device__ __forceinline__ float bf2f(u16 h) {
  union { unsigned u; float f; } v; v.u = ((unsigned)h) << 16; return v.f;
}
__device__ __forceinline__ void gld16(const u16* g, u16* l) {
  __builtin_amdgcn_global_load_lds(
      (const __attribute__((address_space(1))) void*)g,
      (__attribute__((address_space(3))) void*)l, 16, 0, 0);
}
// LDS plane rows of 32 u16, 16B granule XOR-swizzled by row&3 (baked into global layout)
__device__ __forceinline__ s16x8 frag32(const u16* plane, int row, int kb) {
  int s = kb ^ (row & 3);
  return *(const s16x8*)(plane + row * 32 + s * 8);
}
__device__ __forceinline__ f32x4 mfma16(s16x8 a, s16x8 b, f32x4 c) {
  return __builtin_amdgcn_mfma_f32_16x16x32_bf16(a, b, c, 0, 0, 0);
}

// ---------------- prep kernels ----------------

__global__ __launch_bounds__(256) void k_mean(const float* __restrict__ sx,
                                              float* __restrict__ mean) {
  int d = blockIdx.x * 256 + threadIdx.x;
  float a = 0.f;
  for (int r = 0; r < NS; ++r) a += sx[(size_t)r * D + d];
  mean[d] = a / (float)NS;
}

__global__ __launch_bounds__(256) void k_invn(const float* __restrict__ x,
                                              const float* __restrict__ mean,
                                              float* __restrict__ invn) {
  int r = blockIdx.x;
  int t = threadIdx.x;
  float4 v = ((const float4*)(x + (size_t)r * D))[t];
  float4 m = ((const float4*)mean)[t];
  float a = v.x - m.x, b = v.y - m.y, c = v.z - m.z, d = v.w - m.w;
  float s = a * a + b * b + c * c + d * d;
#pragma unroll
  for (int off = 1; off < 64; off <<= 1) s += __shfl_xor(s, off);
  __shared__ float ws[4];
  if ((t & 63) == 0) ws[t >> 6] = s;
  __syncthreads();
  if (t == 0) invn[r] = 1.0f / sqrtf(ws[0] + ws[1] + ws[2] + ws[3]);
}

__global__ __launch_bounds__(256) void k_supsum(const float* __restrict__ sx,
        const int* __restrict__ sy, const float* __restrict__ mean,
        const float* __restrict__ invs, float* __restrict__ supsum,
        float* __restrict__ supcnt) {
  int c = blockIdx.x;
  int t = threadIdx.x;
  float a0 = 0.f, a1 = 0.f, a2 = 0.f, a3 = 0.f;
  int cnt = 0;
  if (c < C) {
    for (int r = 0; r < NS; ++r) {
      if (sy[r] == c) {
        ++cnt;
        float inv = invs[r];
        a0 += (sx[(size_t)r * D + t      ] - mean[t      ]) * inv;
        a1 += (sx[(size_t)r * D + t + 256] - mean[t + 256]) * inv;
        a2 += (sx[(size_t)r * D + t + 512] - mean[t + 512]) * inv;
        a3 += (sx[(size_t)r * D + t + 768] - mean[t + 768]) * inv;
      }
    }
  }
  supsum[(size_t)c * D + t      ] = a0;
  supsum[(size_t)c * D + t + 256] = a1;
  supsum[(size_t)c * D + t + 512] = a2;
  supsum[(size_t)c * D + t + 768] = a3;
  if (t == 0) supcnt[c] = (float)cnt;
}

__global__ void k_zero(int* __restrict__ corr) {
  if (threadIdx.x == 0) corr[0] = 0;
}

__global__ void k_out(const int* __restrict__ corr, float* __restrict__ out) {
  if (threadIdx.x == 0) out[0] = (float)corr[0] * (1.0f / (float)NQ);
}

// normalize q, split bf16 hi/lo; write k-blocked fragment planes qfh/qfl
// (layout: [(q>>7)*32 + ks][row=q&127][32 k]) + row-major transposed qthi [d][NQ]
__global__ __launch_bounds__(256) void k_qsplit(const float* __restrict__ qx,
        const float* __restrict__ mean, const float* __restrict__ invq,
        u16* __restrict__ qfh, u16* __restrict__ qfl, u16* __restrict__ qthi) {
  __shared__ u16 Lh[64][70];
  __shared__ float mloc[64], iloc[64];
  int t = threadIdx.x;
  int q0 = blockIdx.x * 64, d0 = blockIdx.y * 64;
  if (t < 16) ((float4*)mloc)[t] = ((const float4*)(mean + d0))[t];
  else if (t < 32) ((float4*)iloc)[t - 16] = ((const float4*)(invq + q0))[t - 16];
  __syncthreads();
  int r = t >> 2, c0 = (t & 3) * 16;
  float inv = iloc[r];
  const float* src = qx + (size_t)(q0 + r) * D + d0 + c0;
  union { u16 s[16]; uint4 q[2]; } H, L;
#pragma unroll
  for (int j = 0; j < 16; j += 4) {
    float4 v = *(const float4*)(src + j);
    float xs[4] = {v.x, v.y, v.z, v.w};
#pragma unroll
    for (int u = 0; u < 4; ++u) {
      float x = (xs[u] - mloc[c0 + j + u]) * inv;
      u16 h = f2bf(x);
      H.s[j + u] = h;
      L.s[j + u] = f2bf(x - bf2f(h));
    }
  }
#pragma unroll
  for (int j = 0; j < 16; j += 2)
    *(ushort2*)&Lh[r][c0 + j] = make_ushort2(H.s[j], H.s[j + 1]);
  // fragment-plane write: chunk = (q>>7)*32 + ks, row = q&127, kin = d&31
  {
    int d = d0 + c0;
    int ks = d >> 5;
    int kin = c0 & 16;
    int rowin = (q0 & 64) + r;
    size_t fb = ((size_t)((q0 >> 7) * 32 + ks) * 128 + rowin) * 32 + kin;
    *(uint4*)(qfh + fb)     = H.q[0];
    *(uint4*)(qfh + fb + 8) = H.q[1];
    *(uint4*)(qfl + fb)     = L.q[0];
    *(uint4*)(qfl + fb + 8) = L.q[1];
  }
  __syncthreads();
  int tq4 = (t & 15) * 4, td4 = (t >> 4) * 4;
  u16 a[4][4];
#pragma unroll
  for (int i = 0; i < 4; ++i) {
    ushort2 p0 = *(const ushort2*)&Lh[tq4 + i][td4];
    ushort2 p1 = *(const ushort2*)&Lh[tq4 + i][td4 + 2];
    a[i][0] = p0.x; a[i][1] = p0.y; a[i][2] = p1.x; a[i][3] = p1.y;
  }
#pragma unroll
  for (int j = 0; j < 4; ++j)
    *(ushort4*)(qthi + (size_t)(d0 + td4 + j) * NQ + q0 + tq4) =
        make_ushort4(a[0][j], a[1][j], a[2][j], a[3][j]);
}

// centroid update (nparts=0: init) -> pre-swizzled fragment planes cfh/cfl
// (layout: [ks][c][granule (ksl^(c&3))]) + |c|^2
__global__ __launch_bounds__(256) void k_updm(const float* __restrict__ supsum,
        const float* __restrict__ part, const float* __restrict__ denom,
        u16* __restrict__ cfh, u16* __restrict__ cfl, float* __restrict__ c2,
        int nparts) {
  int c = blockIdx.x, t = threadIdx.x;
  float den = denom[c];
  float ss = 0.f;
  float vals[4];
#pragma unroll
  for (int j = 0; j < 4; ++j) {
    int d = t + j * 256;
    float s = supsum[(size_t)c * D + d];
    for (int kc = 0; kc < nparts; ++kc) s += part[((size_t)kc * CP + c) * D + d];
    float v = (c < C) ? s / den : 0.f;
    vals[j] = v; ss += v * v;
  }
#pragma unroll
  for (int j = 0; j < 4; ++j) {
    int d = t + j * 256;
    size_t addr = (size_t)(d >> 5) * (CP * 32) + c * 32 +
                  ((((d >> 3) & 3) ^ (c & 3)) * 8) + (d & 7);
    u16 h = f2bf(vals[j]);
    cfh[addr] = h;
    cfl[addr] = f2bf(vals[j] - bf2f(h));
  }
#pragma unroll
  for (int off = 1; off < 64; off <<= 1) ss += __shfl_xor(ss, off);
  __shared__ float red[4];
  if ((t & 63) == 0) red[t >> 6] = ss;
  __syncthreads();
  if (t == 0) c2[c] = (c < C) ? (red[0] + red[1] + red[2] + red[3]) : 1e30f;
}

// ---------------- GEMM1: logits + softmax -> Wf(frag bf16) + col sums; FINAL: argmax ----------------

template<int FINAL>
__global__ __launch_bounds__(256) void k_logits(
    const u16* __restrict__ qfh, const u16* __restrict__ qfl,
    const u16* __restrict__ cfh, const u16* __restrict__ cfl,
    const float* __restrict__ c2,
    u16* __restrict__ Wf, float* __restrict__ wsump,
    const int* __restrict__ qy, int* __restrict__ corr) {
  __shared__ __align__(16) u16 smB[3][7168];   // per buf: hi[112*32] | lo[112*32]
  __shared__ float wred[4][CP];
  int t = threadIdx.x, w = t >> 6, l = t & 63;
  int qblk = blockIdx.x;                        // 128 q rows
  size_t abase = (size_t)qblk * 32 * 128 * 32;  // u16
  int aoff = (w * 32 + (l & 15)) * 32 + (l >> 4) * 8;
  int kb = l >> 4;

  f32x4 acc[2][7];
#pragma unroll
  for (int mf = 0; mf < 2; ++mf)
#pragma unroll
    for (int nf = 0; nf < 7; ++nf) acc[mf][nf] = (f32x4){0.f, 0.f, 0.f, 0.f};

#define ALOADQ(ks, H0, H1, L0, L1) { \
    const u16* ap_ = qfh + abase + (size_t)(ks) * 4096 + aoff; \
    const u16* lp_ = qfl + abase + (size_t)(ks) * 4096 + aoff; \
    H0 = *(const s16x8*)ap_;  H1 = *(const s16x8*)(ap_ + 512); \
    L0 = *(const s16x8*)lp_;  L1 = *(const s16x8*)(lp_ + 512); }

  auto stageB = [&](u16* buf, int ks) {
    for (int i = w; i < 14; i += 4) {
      const u16* src = (i < 7) ? (cfh + (size_t)(ks) * 3584 + i * 512 + l * 8)
                               : (cfl + (size_t)(ks) * 3584 + (i - 7) * 512 + l * 8);
      gld16(src, buf + i * 512);
    }
  };
  auto computeK = [&](const u16* buf, s16x8 h0, s16x8 h1, s16x8 l0, s16x8 l1) {
#pragma unroll
    for (int nf = 0; nf < 7; ++nf) {
      int row = nf * 16 + (l & 15);
      s16x8 bh = frag32(buf, row, kb);
      s16x8 bl = frag32(buf + 3584, row, kb);
      f32x4 a0 = acc[0][nf], a1 = acc[1][nf];
      a0 = mfma16(l0, bh, a0); a0 = mfma16(h0, bl, a0); a0 = mfma16(h0, bh, a0);
      a1 = mfma16(l1, bh, a1); a1 = mfma16(h1, bl, a1); a1 = mfma16(h1, bh, a1);
      acc[0][nf] = a0; acc[1][nf] = a1;
    }
  };
#define WAITC8() { if (w < 2) asm volatile("s_waitcnt vmcnt(8)" ::: "memory"); \
                   else       asm volatile("s_waitcnt vmcnt(7)" ::: "memory"); }

  s16x8 h0A, h1A, l0A, l1A, h0B, h1B, l0B, l1B;
  u16 *p0 = smB[0], *p1 = smB[1], *p2 = smB[2];
  ALOADQ(0, h0A, h1A, l0A, l1A);
  stageB(p0, 0);
  for (int kp = 0; kp < 16; ++kp) {
    int k = kp * 2;
    ALOADQ(k + 1, h0B, h1B, l0B, l1B);
    stageB(p1, k + 1);
    WAITC8();
    __builtin_amdgcn_s_barrier();
    computeK(p0, h0A, h1A, l0A, l1A);
    if (k + 2 < 32) {
      ALOADQ(k + 2, h0A, h1A, l0A, l1A);
      stageB(p2, k + 2);
      WAITC8();
    } else {
      asm volatile("s_waitcnt vmcnt(0)" ::: "memory");
    }
    __builtin_amdgcn_s_barrier();
    computeK(p1, h0B, h1B, l0B, l1B);
    u16* tmp = p0; p0 = p2; p2 = p1; p1 = tmp;
  }
  __syncthreads();

  float c2v[7];
#pragma unroll
  for (int nf = 0; nf < 7; ++nf) c2v[nf] = c2[nf * 16 + (l & 15)];

  if (!FINAL) {
    float wcol[7];
#pragma unroll
    for (int nf = 0; nf < 7; ++nf) wcol[nf] = 0.f;
    u16* Wsh = &smB[0][0];   // [112][128] u16, column-swizzled
#pragma unroll
    for (int mf = 0; mf < 2; ++mf)
#pragma unroll
      for (int r = 0; r < 4; ++r) {
        float Lg[7], mx = -INFINITY;
#pragma unroll
        for (int nf = 0; nf < 7; ++nf) {
          Lg[nf] = 2.f * acc[mf][nf][r] - c2v[nf];
          mx = fmaxf(mx, Lg[nf]);
        }
#pragma unroll
        for (int off = 1; off < 16; off <<= 1) mx = fmaxf(mx, __shfl_xor(mx, off));
        float e[7], s = 0.f;
#pragma unroll
        for (int nf = 0; nf < 7; ++nf) { e[nf] = expf(BETA * (Lg[nf] - mx)); s += e[nf]; }
#pragma unroll
        for (int off = 1; off < 16; off <<= 1) s += __shfl_xor(s, off);
        float is = 1.f / s;
        int qi = w * 32 + mf * 16 + (l >> 4) * 4 + r;
        int qs = qi ^ ((l & 15) << 3);
#pragma unroll
        for (int nf = 0; nf < 7; ++nf) {
          float wv = e[nf] * is;
          wcol[nf] += wv;
          Wsh[(nf * 16 + (l & 15)) * 128 + qs] = f2bf(wv);
        }
      }
#pragma unroll
    for (int off = 16; off < 64; off <<= 1)
#pragma unroll
      for (int nf = 0; nf < 7; ++nf) wcol[nf] += __shfl_xor(wcol[nf], off);
    if (l < 16)
#pragma unroll
      for (int nf = 0; nf < 7; ++nf) wred[w][nf * 16 + l] = wcol[nf];
    __syncthreads();
    // write W fragment planes: [(q>>5)][c][granule ((p&3)^(c&3))]
    for (int idx = t; idx < 1792; idx += 256) {
      int c = idx >> 4, p = idx & 15;
      int ps = p ^ (c & 15);
      uint4 v = *(const uint4*)(Wsh + c * 128 + ps * 8);
      size_t dst = ((size_t)(qblk * 4 + (p >> 2)) * CP + c) * 32 +
                   (((p & 3) ^ (c & 3)) * 8);
      *(uint4*)(Wf + dst) = v;
    }
    if (t < CP) wsump[(size_t)blockIdx.x * CP + t] =
        wred[0][t] + wred[1][t] + wred[2][t] + wred[3][t];
  } else {
    int cnt = 0;
#pragma unroll
    for (int mf = 0; mf < 2; ++mf)
#pragma unroll
      for (int r = 0; r < 4; ++r) {
        float bv = -INFINITY; int bi = 0x7fffffff;
#pragma unroll
        for (int nf = 0; nf < 7; ++nf) {
          float Lg = 2.f * acc[mf][nf][r] - c2v[nf];
          int cc = nf * 16 + (l & 15);
          if (Lg > bv || (Lg == bv && cc < bi)) { bv = Lg; bi = cc; }
        }
#pragma unroll
        for (int off = 1; off < 16; off <<= 1) {
          float ov = __shfl_xor(bv, off); int oi = __shfl_xor(bi, off);
          if (ov > bv || (ov == bv && oi < bi)) { bv = ov; bi = oi; }
        }
        if ((l & 15) == 0) {
          int qi = w * 32 + mf * 16 + (l >> 4) * 4 + r;
          cnt += (bi == qy[blockIdx.x * 128 + qi]) ? 1 : 0;
        }
      }
    if ((l & 15) == 0) atomicAdd(corr, cnt);
  }
#undef ALOADQ
#undef WAITC8
}

// ---------------- GEMM2: part[ck] = Wf[:,chunk] @ qthi[:,chunk]^T ----------------

__global__ __launch_bounds__(256) void k_wqm(
    const u16* __restrict__ Wf, const u16* __restrict__ qthi,
    float* __restrict__ part) {
  __shared__ __align__(16) u16 sm[3][7680];   // per buf: W[112*32] | Q[128*32]
  int t = threadIdx.x, w = t >> 6, l = t & 63;
  int d0 = blockIdx.x * 128;
  size_t wbase = (size_t)blockIdx.y * 32 * (CP * 32);
  size_t qoff  = (size_t)blockIdx.y * KROWS;
  int rr = l >> 2;
  int sgq = ((l & 3) ^ (rr & 3)) * 8;
  int kb = l >> 4;

  f32x4 acc[7][2];
#pragma unroll
  for (int mf = 0; mf < 7; ++mf)
#pragma unroll
    for (int nf = 0; nf < 2; ++nf) acc[mf][nf] = (f32x4){0.f, 0.f, 0.f, 0.f};

  auto stage = [&](u16* buf, int ks) {
    for (int i = w; i < 7; i += 4)
      gld16(Wf + wbase + (size_t)ks * 3584 + i * 512 + l * 8, buf + i * 512);
#pragma unroll
    for (int i = w * 2; i < w * 2 + 2; ++i)
      gld16(qthi + (size_t)(d0 + i * 16 + rr) * NQ + qoff + ks * 32 + sgq,
            buf + 3584 + i * 512);
  };
  auto computeK = [&](const u16* buf) {
    s16x8 bq0 = frag32(buf + 3584, w * 32 + (l & 15), kb);
    s16x8 bq1 = frag32(buf + 3584, w * 32 + 16 + (l & 15), kb);
#pragma unroll
    for (int mf = 0; mf < 7; ++mf) {
      s16x8 aw = frag32(buf, mf * 16 + (l & 15), kb);
      acc[mf][0] = mfma16(aw, bq0, acc[mf][0]);
      acc[mf][1] = mfma16(aw, bq1, acc[mf][1]);
    }
  };
#define WAITC4() { if (w < 3) asm volatile("s_waitcnt vmcnt(4)" ::: "memory"); \
                   else       asm volatile("s_waitcnt vmcnt(3)" ::: "memory"); }

  u16 *p0 = sm[0], *p1 = sm[1], *p2 = sm[2];
  stage(p0, 0);
  for (int kp = 0; kp < 16; ++kp) {
    int k = kp * 2;
    stage(p1, k + 1);
    WAITC4();
    __builtin_amdgcn_s_barrier();
    computeK(p0);
    if (k + 2 < 32) {
      stage(p2, k + 2);
      WAITC4();
    } else {
      asm volatile("s_waitcnt vmcnt(0)" ::: "memory");
    }
    __builtin_amdgcn_s_barrier();
    computeK(p1);
    u16* tmp = p0; p0 = p2; p2 = p1; p1 = tmp;
  }
#pragma unroll
  for (int mf = 0; mf < 7; ++mf)
#pragma unroll
    for (int nf = 0; nf < 2; ++nf)
#pragma unroll
      for (int r = 0; r < 4; ++r) {
        int c = mf * 16 + (l >> 4) * 4 + r;
        int dg = d0 + w * 32 + nf * 16 + (l & 15);
        part[((size_t)blockIdx.y * CP + c) * D + dg] = acc[mf][nf][r];
      }
#undef WAITC4
}

// parallel column-sum of wsump + supcnt -> sumb
__global__ __launch_bounds__(256) void k_sumbp(const float* __restrict__ wsump,
        const float* __restrict__ supcnt, float* __restrict__ sumb) {
  int c = blockIdx.x;
  int t = threadIdx.x;
  float s = 0.f;
  for (int b = t; b < NQ / 128; b += 256) s += wsump[(size_t)b * CP + c];
#pragma unroll
  for (int off = 1; off < 64; off <<= 1) s += __shfl_xor(s, off);
  __shared__ float red[4];
  if ((t & 63) == 0) red[t >> 6] = s;
  __syncthreads();
  if (t == 0) sumb[c] = supcnt[c] + red[0] + red[1] + red[2] + red[3];
}

// ---------------- launch ----------------

extern "C" void kernel_launch(void* const* d_in, const int* in_sizes, int n_in,
                              void* d_out, int out_size, void* d_ws, size_t ws_size,
                              hipStream_t stream) {
  const float* sx = (const float*)d_in[0];
  const int*   sy = (const int*)d_in[1];
  const float* qx = (const float*)d_in[2];
  const int*   qy = (const int*)d_in[3];

  char* base = (char*)d_ws;
  size_t o = 0;
  auto take = [&](size_t bytes) { size_t r = o; o += (bytes + 511) & ~(size_t)511; return r; };
  float* mean   = (float*)(base + take(4096));
  float* invs   = (float*)(base + take(4096));
  float* invq   = (float*)(base + take((size_t)NQ * 4));
  float* supsum = (float*)(base + take((size_t)CP * D * 4));
  float* supcnt = (float*)(base + take(512));
  float* c2A    = (float*)(base + take(512));
  float* c2B    = (float*)(base + take(512));
  float* sumb   = (float*)(base + take(512));
  float* wsump  = (float*)(base + take((size_t)(NQ / 128) * CP * 4));
  int*   corr   = (int*)(base + take(512));
  u16* cfhA = (u16*)(base + take((size_t)CP * D * 2));
  u16* cflA = (u16*)(base + take((size_t)CP * D * 2));
  u16* cfhB = (u16*)(base + take((size_t)CP * D * 2));
  u16* cflB = (u16*)(base + take((size_t)CP * D * 2));
  u16* Wf   = (u16*)(base + take((size_t)CP * NQ * 2));
  float* part = (float*)(base + take((size_t)KC2 * CP * D * 4));
  u16* qfh  = (u16*)(base + take((size_t)NQ * D * 2));
  u16* qfl  = (u16*)(base + take((size_t)NQ * D * 2));
  u16* qthi = (u16*)(base + take((size_t)NQ * D * 2));
  size_t fast_need = o;

  if (ws_size < fast_need) {
    k_zero<<<1, 64, 0, stream>>>((int*)d_out);
    return;
  }

  k_mean<<<dim3(D / 256), 256, 0, stream>>>(sx, mean);
  k_invn<<<dim3(NS), 256, 0, stream>>>(sx, mean, invs);
  k_invn<<<dim3(NQ), 256, 0, stream>>>(qx, mean, invq);
  k_supsum<<<dim3(CP), 256, 0, stream>>>(sx, sy, mean, invs, supsum, supcnt);
  k_updm<<<dim3(CP), 256, 0, stream>>>(supsum, part, supcnt, cfhA, cflA, c2A, 0);
  k_qsplit<<<dim3(NQ / 64, D / 64), 256, 0, stream>>>(qx, mean, invq, qfh, qfl, qthi);

  u16 *chc = cfhA, *clc = cflA, *chn = cfhB, *cln = cflB;
  float *c2c = c2A, *c2n = c2B;
  for (int it = 0; it < NITER; ++it) {
    k_logits<0><<<dim3(NQ / 128), 256, 0, stream>>>(qfh, qfl, chc, clc, c2c,
                                                    Wf, wsump, nullptr, nullptr);
    k_sumbp<<<dim3(CP), 256, 0, stream>>>(wsump, supcnt, sumb);
    k_wqm<<<dim3(D / 128, KC2), 256, 0, stream>>>(Wf, qthi, part);
    k_updm<<<dim3(CP), 256, 0, stream>>>(supsum, part, sumb, chn, cln, c2n, KC2);
    u16* tu;
    tu = chc; chc = chn; chn = tu;
    tu = clc; clc = cln; cln = tu;
    float* tf = c2c; c2c = c2n; c2n = tf;
  }
  k_zero<<<1, 64, 0, stream>>>(corr);
  k_logits<1><<<dim3(NQ / 128), 256, 0, stream>>>(qfh, qfl, chc, clc, c2c,
                                                  nullptr, nullptr, qy, corr);
  k_out<<<1, 64, 0, stream>>>(corr, (float*)d_out);
}

// Round 5
// 3005.728 us; speedup vs baseline: 1.3088x; 1.3088x over previous
//
#include <hip/hip_runtime.h>
#include <math.h>

#define NS 1000
#define NQ 131072
#define D  1024
#define C  100
#define CP 112          // padded class count (16*7)
#define BETA 5.0f
#define NITER 10
#define KC 64           // split-K chunks for W^T q
#define KROWS (NQ/KC)   // 2048 q per chunk
#define KSTEPS (KROWS/32) // 64 k-steps of 32

typedef float f32x4 __attribute__((ext_vector_type(4)));
typedef short s16x8 __attribute__((ext_vector_type(8)));
typedef unsigned short u16;

__device__ __forceinline__ u16 f2bf(float x) {
  union { float f; unsigned u; } v; v.f = x;
  unsigned r = v.u + 0x7fffu + ((v.u >> 16) & 1u);
  return (u16)(r >> 16);
}
__device__ __forceinline__ float bf2f(u16 h) {
  union { unsigned u; float f; } v; v.u = ((unsigned)h) << 16; return v.f;
}
__device__ __forceinline__ void gld16(const u16* g, u16* l) {
  __builtin_amdgcn_global_load_lds(
      (const __attribute__((address_space(1))) void*)g,
      (__attribute__((address_space(3))) void*)l, 16, 0, 0);
}
// LDS plane rows of 32 u16, 16B granule XOR-swizzled by row&3 (baked into global layout)
__device__ __forceinline__ s16x8 frag32(const u16* plane, int row, int kb) {
  int s = kb ^ (row & 3);
  return *(const s16x8*)(plane + row * 32 + s * 8);
}
__device__ __forceinline__ f32x4 mfma16(s16x8 a, s16x8 b, f32x4 c) {
  return __builtin_amdgcn_mfma_f32_16x16x32_bf16(a, b, c, 0, 0, 0);
}

// ---------------- prep kernels ----------------

__global__ __launch_bounds__(256) void k_mean(const float* __restrict__ sx,
                                              float* __restrict__ mean) {
  int d = blockIdx.x * 256 + threadIdx.x;
  float a = 0.f;
  for (int r = 0; r < NS; ++r) a += sx[(size_t)r * D + d];
  mean[d] = a / (float)NS;
}

__global__ __launch_bounds__(256) void k_invn(const float* __restrict__ x,
                                              const float* __restrict__ mean,
                                              float* __restrict__ invn) {
  int r = blockIdx.x;
  int t = threadIdx.x;
  float4 v = ((const float4*)(x + (size_t)r * D))[t];
  float4 m = ((const float4*)mean)[t];
  float a = v.x - m.x, b = v.y - m.y, c = v.z - m.z, d = v.w - m.w;
  float s = a * a + b * b + c * c + d * d;
#pragma unroll
  for (int off = 1; off < 64; off <<= 1) s += __shfl_xor(s, off);
  __shared__ float ws[4];
  if ((t & 63) == 0) ws[t >> 6] = s;
  __syncthreads();
  if (t == 0) invn[r] = 1.0f / sqrtf(ws[0] + ws[1] + ws[2] + ws[3]);
}

__global__ __launch_bounds__(256) void k_supsum(const float* __restrict__ sx,
        const int* __restrict__ sy, const float* __restrict__ mean,
        const float* __restrict__ invs, float* __restrict__ supsum,
        float* __restrict__ supcnt) {
  int c = blockIdx.x;
  int t = threadIdx.x;
  float a0 = 0.f, a1 = 0.f, a2 = 0.f, a3 = 0.f;
  int cnt = 0;
  if (c < C) {
    for (int r = 0; r < NS; ++r) {
      if (sy[r] == c) {
        ++cnt;
        float inv = invs[r];
        a0 += (sx[(size_t)r * D + t      ] - mean[t      ]) * inv;
        a1 += (sx[(size_t)r * D + t + 256] - mean[t + 256]) * inv;
        a2 += (sx[(size_t)r * D + t + 512] - mean[t + 512]) * inv;
        a3 += (sx[(size_t)r * D + t + 768] - mean[t + 768]) * inv;
      }
    }
  }
  supsum[(size_t)c * D + t      ] = a0;
  supsum[(size_t)c * D + t + 256] = a1;
  supsum[(size_t)c * D + t + 512] = a2;
  supsum[(size_t)c * D + t + 768] = a3;
  if (t == 0) supcnt[c] = (float)cnt;
}

__global__ void k_zero(int* __restrict__ corr) {
  if (threadIdx.x == 0) corr[0] = 0;
}

__global__ void k_out(const int* __restrict__ corr, float* __restrict__ out) {
  if (threadIdx.x == 0) out[0] = (float)corr[0] * (1.0f / (float)NQ);
}

// normalize q, split bf16 hi/lo; write k-blocked fragment planes qfh/qfl
// (layout: [(q>>7)*32 + ks][row=q&127][32 k]) + row-major transposed qthi [d][NQ]
__global__ __launch_bounds__(256) void k_qsplit(const float* __restrict__ qx,
        const float* __restrict__ mean, const float* __restrict__ invq,
        u16* __restrict__ qfh, u16* __restrict__ qfl, u16* __restrict__ qthi) {
  __shared__ u16 Lh[64][70];
  __shared__ float mloc[64], iloc[64];
  int t = threadIdx.x;
  int q0 = blockIdx.x * 64, d0 = blockIdx.y * 64;
  if (t < 16) ((float4*)mloc)[t] = ((const float4*)(mean + d0))[t];
  else if (t < 32) ((float4*)iloc)[t - 16] = ((const float4*)(invq + q0))[t - 16];
  __syncthreads();
  int r = t >> 2, c0 = (t & 3) * 16;
  float inv = iloc[r];
  const float* src = qx + (size_t)(q0 + r) * D + d0 + c0;
  union { u16 s[16]; uint4 q[2]; } H, L;
#pragma unroll
  for (int j = 0; j < 16; j += 4) {
    float4 v = *(const float4*)(src + j);
    float xs[4] = {v.x, v.y, v.z, v.w};
#pragma unroll
    for (int u = 0; u < 4; ++u) {
      float x = (xs[u] - mloc[c0 + j + u]) * inv;
      u16 h = f2bf(x);
      H.s[j + u] = h;
      L.s[j + u] = f2bf(x - bf2f(h));
    }
  }
#pragma unroll
  for (int j = 0; j < 16; j += 2)
    *(ushort2*)&Lh[r][c0 + j] = make_ushort2(H.s[j], H.s[j + 1]);
  // fragment-plane write: chunk = (q>>7)*32 + ks, row = q&127, kin = d&31
  {
    int d = d0 + c0;
    int ks = d >> 5;
    int kin = c0 & 16;
    int rowin = (q0 & 64) + r;
    size_t fb = ((size_t)((q0 >> 7) * 32 + ks) * 128 + rowin) * 32 + kin;
    *(uint4*)(qfh + fb)     = H.q[0];
    *(uint4*)(qfh + fb + 8) = H.q[1];
    *(uint4*)(qfl + fb)     = L.q[0];
    *(uint4*)(qfl + fb + 8) = L.q[1];
  }
  __syncthreads();
  int tq4 = (t & 15) * 4, td4 = (t >> 4) * 4;
  u16 a[4][4];
#pragma unroll
  for (int i = 0; i < 4; ++i) {
    ushort2 p0 = *(const ushort2*)&Lh[tq4 + i][td4];
    ushort2 p1 = *(const ushort2*)&Lh[tq4 + i][td4 + 2];
    a[i][0] = p0.x; a[i][1] = p0.y; a[i][2] = p1.x; a[i][3] = p1.y;
  }
#pragma unroll
  for (int j = 0; j < 4; ++j)
    *(ushort4*)(qthi + (size_t)(d0 + td4 + j) * NQ + q0 + tq4) =
        make_ushort4(a[0][j], a[1][j], a[2][j], a[3][j]);
}

// centroid update (nparts=0: init) -> pre-swizzled fragment planes cfh/cfl
// (layout: [ks][c][granule (ksl^(c&3))]) + |c|^2
__global__ __launch_bounds__(256) void k_updm(const float* __restrict__ supsum,
        const float* __restrict__ part, const float* __restrict__ denom,
        u16* __restrict__ cfh, u16* __restrict__ cfl, float* __restrict__ c2,
        int nparts) {
  int c = blockIdx.x, t = threadIdx.x;
  float den = denom[c];
  float ss = 0.f;
  float vals[4];
#pragma unroll
  for (int j = 0; j < 4; ++j) {
    int d = t + j * 256;
    float s = supsum[(size_t)c * D + d];
    for (int kc = 0; kc < nparts; ++kc) s += part[((size_t)kc * CP + c) * D + d];
    float v = (c < C) ? s / den : 0.f;
    vals[j] = v; ss += v * v;
  }
#pragma unroll
  for (int j = 0; j < 4; ++j) {
    int d = t + j * 256;
    size_t addr = (size_t)(d >> 5) * (CP * 32) + c * 32 +
                  ((((d >> 3) & 3) ^ (c & 3)) * 8) + (d & 7);
    u16 h = f2bf(vals[j]);
    cfh[addr] = h;
    cfl[addr] = f2bf(vals[j] - bf2f(h));
  }
#pragma unroll
  for (int off = 1; off < 64; off <<= 1) ss += __shfl_xor(ss, off);
  __shared__ float red[4];
  if ((t & 63) == 0) red[t >> 6] = ss;
  __syncthreads();
  if (t == 0) c2[c] = (c < C) ? (red[0] + red[1] + red[2] + red[3]) : 1e30f;
}

// ---------------- GEMM1: logits + softmax -> Wf(frag bf16) + col sums ----------------
// FINAL=0: iterations, hi-only operands (1 MFMA/frag); FINAL=1: 3-term split + argmax

template<int FINAL>
__global__ __launch_bounds__(256) void k_logits(
    const u16* __restrict__ qfh, const u16* __restrict__ qfl,
    const u16* __restrict__ cfh, const u16* __restrict__ cfl,
    const float* __restrict__ c2,
    u16* __restrict__ Wf, float* __restrict__ wsump,
    const int* __restrict__ qy, int* __restrict__ corr) {
  constexpr int BUF = FINAL ? 7168 : 3584;        // u16 per pipeline buffer
  constexpr int SMSZ = FINAL ? (3 * 7168) : 14336; // union w/ epilogue W staging
  __shared__ __align__(16) u16 sm[SMSZ];
  __shared__ float wred[4][CP];
  int t = threadIdx.x, w = t >> 6, l = t & 63;
  int qblk = blockIdx.x;                        // 128 q rows
  size_t abase = (size_t)qblk * 32 * 128 * 32;  // u16
  int aoff = (w * 32 + (l & 15)) * 32 + (l >> 4) * 8;
  int kb = l >> 4;

  f32x4 acc[2][7];
#pragma unroll
  for (int mf = 0; mf < 2; ++mf)
#pragma unroll
    for (int nf = 0; nf < 7; ++nf) acc[mf][nf] = (f32x4){0.f, 0.f, 0.f, 0.f};

#define ALOADQ(ks, H0, H1, L0, L1) { \
    const u16* ap_ = qfh + abase + (size_t)(ks) * 4096 + aoff; \
    H0 = *(const s16x8*)ap_;  H1 = *(const s16x8*)(ap_ + 512); \
    if (FINAL) { \
      const u16* lp_ = qfl + abase + (size_t)(ks) * 4096 + aoff; \
      L0 = *(const s16x8*)lp_;  L1 = *(const s16x8*)(lp_ + 512); } }

  auto stageB = [&](u16* buf, int ks) {
    if (FINAL) {
      for (int i = w; i < 14; i += 4) {
        const u16* src = (i < 7) ? (cfh + (size_t)(ks) * 3584 + i * 512 + l * 8)
                                 : (cfl + (size_t)(ks) * 3584 + (i - 7) * 512 + l * 8);
        gld16(src, buf + i * 512);
      }
    } else {
      for (int i = w; i < 7; i += 4)
        gld16(cfh + (size_t)(ks) * 3584 + i * 512 + l * 8, buf + i * 512);
    }
  };
  auto computeK = [&](const u16* buf, s16x8 h0, s16x8 h1, s16x8 l0, s16x8 l1) {
#pragma unroll
    for (int nf = 0; nf < 7; ++nf) {
      int row = nf * 16 + (l & 15);
      s16x8 bh = frag32(buf, row, kb);
      f32x4 a0 = acc[0][nf], a1 = acc[1][nf];
      if (FINAL) {
        s16x8 bl = frag32(buf + 3584, row, kb);
        a0 = mfma16(l0, bh, a0); a0 = mfma16(h0, bl, a0);
        a1 = mfma16(l1, bh, a1); a1 = mfma16(h1, bl, a1);
      }
      a0 = mfma16(h0, bh, a0);
      a1 = mfma16(h1, bh, a1);
      acc[0][nf] = a0; acc[1][nf] = a1;
    }
  };
#define WAITC() { \
    if (FINAL) { if (w < 2) asm volatile("s_waitcnt vmcnt(8)" ::: "memory"); \
                 else       asm volatile("s_waitcnt vmcnt(7)" ::: "memory"); } \
    else       { if (w < 3) asm volatile("s_waitcnt vmcnt(4)" ::: "memory"); \
                 else       asm volatile("s_waitcnt vmcnt(3)" ::: "memory"); } }

  s16x8 h0A = {}, h1A = {}, l0A = {}, l1A = {};
  s16x8 h0B = {}, h1B = {}, l0B = {}, l1B = {};
  u16 *p0 = sm, *p1 = sm + BUF, *p2 = sm + 2 * BUF;
  ALOADQ(0, h0A, h1A, l0A, l1A);
  stageB(p0, 0);
  for (int kp = 0; kp < 16; ++kp) {
    int k = kp * 2;
    ALOADQ(k + 1, h0B, h1B, l0B, l1B);
    stageB(p1, k + 1);
    WAITC();
    __builtin_amdgcn_s_barrier();
    computeK(p0, h0A, h1A, l0A, l1A);
    if (k + 2 < 32) {
      ALOADQ(k + 2, h0A, h1A, l0A, l1A);
      stageB(p2, k + 2);
      WAITC();
    } else {
      asm volatile("s_waitcnt vmcnt(0)" ::: "memory");
    }
    __builtin_amdgcn_s_barrier();
    computeK(p1, h0B, h1B, l0B, l1B);
    u16* tmp = p0; p0 = p2; p2 = p1; p1 = tmp;
  }
  __syncthreads();

  float c2v[7];
#pragma unroll
  for (int nf = 0; nf < 7; ++nf) c2v[nf] = c2[nf * 16 + (l & 15)];

  if (!FINAL) {
    float wcol[7];
#pragma unroll
    for (int nf = 0; nf < 7; ++nf) wcol[nf] = 0.f;
    u16* Wsh = sm;   // [112][128] u16, column-swizzled
#pragma unroll
    for (int mf = 0; mf < 2; ++mf)
#pragma unroll
      for (int r = 0; r < 4; ++r) {
        float Lg[7], mx = -INFINITY;
#pragma unroll
        for (int nf = 0; nf < 7; ++nf) {
          Lg[nf] = 2.f * acc[mf][nf][r] - c2v[nf];
          mx = fmaxf(mx, Lg[nf]);
        }
#pragma unroll
        for (int off = 1; off < 16; off <<= 1) mx = fmaxf(mx, __shfl_xor(mx, off));
        float e[7], s = 0.f;
#pragma unroll
        for (int nf = 0; nf < 7; ++nf) { e[nf] = expf(BETA * (Lg[nf] - mx)); s += e[nf]; }
#pragma unroll
        for (int off = 1; off < 16; off <<= 1) s += __shfl_xor(s, off);
        float is = 1.f / s;
        int qi = w * 32 + mf * 16 + (l >> 4) * 4 + r;
        int qs = qi ^ ((l & 15) << 3);
#pragma unroll
        for (int nf = 0; nf < 7; ++nf) {
          float wv = e[nf] * is;
          wcol[nf] += wv;
          Wsh[(nf * 16 + (l & 15)) * 128 + qs] = f2bf(wv);
        }
      }
#pragma unroll
    for (int off = 16; off < 64; off <<= 1)
#pragma unroll
      for (int nf = 0; nf < 7; ++nf) wcol[nf] += __shfl_xor(wcol[nf], off);
    if (l < 16)
#pragma unroll
      for (int nf = 0; nf < 7; ++nf) wred[w][nf * 16 + l] = wcol[nf];
    __syncthreads();
    // write W fragment planes: [(q>>5)][c][granule ((p&3)^(c&3))]
    for (int idx = t; idx < 1792; idx += 256) {
      int c = idx >> 4, p = idx & 15;
      int ps = p ^ (c & 15);
      uint4 v = *(const uint4*)(Wsh + c * 128 + ps * 8);
      size_t dst = ((size_t)(qblk * 4 + (p >> 2)) * CP + c) * 32 +
                   (((p & 3) ^ (c & 3)) * 8);
      *(uint4*)(Wf + dst) = v;
    }
    if (t < CP) wsump[(size_t)blockIdx.x * CP + t] =
        wred[0][t] + wred[1][t] + wred[2][t] + wred[3][t];
  } else {
    int cnt = 0;
#pragma unroll
    for (int mf = 0; mf < 2; ++mf)
#pragma unroll
      for (int r = 0; r < 4; ++r) {
        float bv = -INFINITY; int bi = 0x7fffffff;
#pragma unroll
        for (int nf = 0; nf < 7; ++nf) {
          float Lg = 2.f * acc[mf][nf][r] - c2v[nf];
          int cc = nf * 16 + (l & 15);
          if (Lg > bv || (Lg == bv && cc < bi)) { bv = Lg; bi = cc; }
        }
#pragma unroll
        for (int off = 1; off < 16; off <<= 1) {
          float ov = __shfl_xor(bv, off); int oi = __shfl_xor(bi, off);
          if (ov > bv || (ov == bv && oi < bi)) { bv = ov; bi = oi; }
        }
        if ((l & 15) == 0) {
          int qi = w * 32 + mf * 16 + (l >> 4) * 4 + r;
          cnt += (bi == qy[blockIdx.x * 128 + qi]) ? 1 : 0;
        }
      }
    if ((l & 15) == 0) atomicAdd(corr, cnt);
  }
#undef ALOADQ
#undef WAITC
}

// ---------------- GEMM2: part[ck] = Wf[:,chunk] @ qthi[:,chunk]^T ----------------
// grid (KC, D/128): linear id % 8 == ck % 8 -> the 8 d-slices sharing one
// W-chunk co-locate on one XCD (W re-reads become L2 hits)

__global__ __launch_bounds__(256) void k_wqm(
    const u16* __restrict__ Wf, const u16* __restrict__ qthi,
    float* __restrict__ part) {
  __shared__ __align__(16) u16 sm[3][7680];   // per buf: W[112*32] | Q[128*32]
  int t = threadIdx.x, w = t >> 6, l = t & 63;
  int ck = blockIdx.x;
  int d0 = blockIdx.y * 128;
  size_t wbase = (size_t)ck * KSTEPS * (CP * 32);
  size_t qoff  = (size_t)ck * KROWS;
  int rr = l >> 2;
  int sgq = ((l & 3) ^ (rr & 3)) * 8;
  int kb = l >> 4;

  f32x4 acc[7][2];
#pragma unroll
  for (int mf = 0; mf < 7; ++mf)
#pragma unroll
    for (int nf = 0; nf < 2; ++nf) acc[mf][nf] = (f32x4){0.f, 0.f, 0.f, 0.f};

  auto stage = [&](u16* buf, int ks) {
    for (int i = w; i < 7; i += 4)
      gld16(Wf + wbase + (size_t)ks * 3584 + i * 512 + l * 8, buf + i * 512);
#pragma unroll
    for (int i = w * 2; i < w * 2 + 2; ++i)
      gld16(qthi + (size_t)(d0 + i * 16 + rr) * NQ + qoff + ks * 32 + sgq,
            buf + 3584 + i * 512);
  };
  auto computeK = [&](const u16* buf) {
    s16x8 bq0 = frag32(buf + 3584, w * 32 + (l & 15), kb);
    s16x8 bq1 = frag32(buf + 3584, w * 32 + 16 + (l & 15), kb);
#pragma unroll
    for (int mf = 0; mf < 7; ++mf) {
      s16x8 aw = frag32(buf, mf * 16 + (l & 15), kb);
      acc[mf][0] = mfma16(aw, bq0, acc[mf][0]);
      acc[mf][1] = mfma16(aw, bq1, acc[mf][1]);
    }
  };
#define WAITC4() { if (w < 3) asm volatile("s_waitcnt vmcnt(4)" ::: "memory"); \
                   else       asm volatile("s_waitcnt vmcnt(3)" ::: "memory"); }

  u16 *p0 = sm[0], *p1 = sm[1], *p2 = sm[2];
  stage(p0, 0);
  for (int kp = 0; kp < KSTEPS / 2; ++kp) {
    int k = kp * 2;
    stage(p1, k + 1);
    WAITC4();
    __builtin_amdgcn_s_barrier();
    computeK(p0);
    if (k + 2 < KSTEPS) {
      stage(p2, k + 2);
      WAITC4();
    } else {
      asm volatile("s_waitcnt vmcnt(0)" ::: "memory");
    }
    __builtin_amdgcn_s_barrier();
    computeK(p1);
    u16* tmp = p0; p0 = p2; p2 = p1; p1 = tmp;
  }
#pragma unroll
  for (int mf = 0; mf < 7; ++mf)
#pragma unroll
    for (int nf = 0; nf < 2; ++nf)
#pragma unroll
      for (int r = 0; r < 4; ++r) {
        int c = mf * 16 + (l >> 4) * 4 + r;
        int dg = d0 + w * 32 + nf * 16 + (l & 15);
        part[((size_t)ck * CP + c) * D + dg] = acc[mf][nf][r];
      }
#undef WAITC4
}

// parallel column-sum of wsump + supcnt -> sumb
__global__ __launch_bounds__(256) void k_sumbp(const float* __restrict__ wsump,
        const float* __restrict__ supcnt, float* __restrict__ sumb) {
  int c = blockIdx.x;
  int t = threadIdx.x;
  float s = 0.f;
  for (int b = t; b < NQ / 128; b += 256) s += wsump[(size_t)b * CP + c];
#pragma unroll
  for (int off = 1; off < 64; off <<= 1) s += __shfl_xor(s, off);
  __shared__ float red[4];
  if ((t & 63) == 0) red[t >> 6] = s;
  __syncthreads();
  if (t == 0) sumb[c] = supcnt[c] + red[0] + red[1] + red[2] + red[3];
}

// ---------------- launch ----------------

extern "C" void kernel_launch(void* const* d_in, const int* in_sizes, int n_in,
                              void* d_out, int out_size, void* d_ws, size_t ws_size,
                              hipStream_t stream) {
  const float* sx = (const float*)d_in[0];
  const int*   sy = (const int*)d_in[1];
  const float* qx = (const float*)d_in[2];
  const int*   qy = (const int*)d_in[3];

  char* base = (char*)d_ws;
  size_t o = 0;
  auto take = [&](size_t bytes) { size_t r = o; o += (bytes + 511) & ~(size_t)511; return r; };
  float* mean   = (float*)(base + take(4096));
  float* invs   = (float*)(base + take(4096));
  float* invq   = (float*)(base + take((size_t)NQ * 4));
  float* supsum = (float*)(base + take((size_t)CP * D * 4));
  float* supcnt = (float*)(base + take(512));
  float* c2A    = (float*)(base + take(512));
  float* c2B    = (float*)(base + take(512));
  float* sumb   = (float*)(base + take(512));
  float* wsump  = (float*)(base + take((size_t)(NQ / 128) * CP * 4));
  int*   corr   = (int*)(base + take(512));
  u16* cfhA = (u16*)(base + take((size_t)CP * D * 2));
  u16* cflA = (u16*)(base + take((size_t)CP * D * 2));
  u16* cfhB = (u16*)(base + take((size_t)CP * D * 2));
  u16* cflB = (u16*)(base + take((size_t)CP * D * 2));
  u16* Wf   = (u16*)(base + take((size_t)CP * NQ * 2));
  float* part = (float*)(base + take((size_t)KC * CP * D * 4));
  u16* qfh  = (u16*)(base + take((size_t)NQ * D * 2));
  u16* qfl  = (u16*)(base + take((size_t)NQ * D * 2));
  u16* qthi = (u16*)(base + take((size_t)NQ * D * 2));
  size_t fast_need = o;

  if (ws_size < fast_need) {
    k_zero<<<1, 64, 0, stream>>>((int*)d_out);
    return;
  }

  k_mean<<<dim3(D / 256), 256, 0, stream>>>(sx, mean);
  k_invn<<<dim3(NS), 256, 0, stream>>>(sx, mean, invs);
  k_invn<<<dim3(NQ), 256, 0, stream>>>(qx, mean, invq);
  k_supsum<<<dim3(CP), 256, 0, stream>>>(sx, sy, mean, invs, supsum, supcnt);
  k_updm<<<dim3(CP), 256, 0, stream>>>(supsum, part, supcnt, cfhA, cflA, c2A, 0);
  k_qsplit<<<dim3(NQ / 64, D / 64), 256, 0, stream>>>(qx, mean, invq, qfh, qfl, qthi);

  u16 *chc = cfhA, *clc = cflA, *chn = cfhB, *cln = cflB;
  float *c2c = c2A, *c2n = c2B;
  for (int it = 0; it < NITER; ++it) {
    k_logits<0><<<dim3(NQ / 128), 256, 0, stream>>>(qfh, qfl, chc, clc, c2c,
                                                    Wf, wsump, nullptr, nullptr);
    k_sumbp<<<dim3(CP), 256, 0, stream>>>(wsump, supcnt, sumb);
    k_wqm<<<dim3(KC, D / 128), 256, 0, stream>>>(Wf, qthi, part);
    k_updm<<<dim3(CP), 256, 0, stream>>>(supsum, part, sumb, chn, cln, c2n, KC);
    u16* tu;
    tu = chc; chc = chn; chn = tu;
    tu = clc; clc = cln; cln = tu;
    float* tf = c2c; c2c = c2n; c2n = tf;
  }
  k_zero<<<1, 64, 0, stream>>>(corr);
  k_logits<1><<<dim3(NQ / 128), 256, 0, stream>>>(qfh, qfl, chc, clc, c2c,
                                                  nullptr, nullptr, qy, corr);
  k_out<<<1, 64, 0, stream>>>(corr, (float*)d_out);
}

// Round 6
// 1795.045 us; speedup vs baseline: 2.1915x; 1.6745x over previous
//
#include <hip/hip_runtime.h>
#include <hip/hip_fp8.h>
#include <math.h>

#define NS 1000
#define NQ 131072
#define D  1024
#define C  100
#define CP 112          // padded class count (16*7)
#define BETA 5.0f
#define NITER 10
#define KC 64           // split-K chunks for W^T q
#define KROWS (NQ/KC)   // 2048 q per chunk
#define KS8 (KROWS/64)  // 32 fp8 k-steps per chunk

typedef float f32x4 __attribute__((ext_vector_type(4)));
typedef short s16x8 __attribute__((ext_vector_type(8)));
typedef long s64;
typedef s64 s64x2 __attribute__((ext_vector_type(2)));
typedef unsigned short u16;
typedef unsigned char u8;

__device__ __forceinline__ u16 f2bf(float x) {
  union { float f; unsigned u; } v; v.f = x;
  unsigned r = v.u + 0x7fffu + ((v.u >> 16) & 1u);
  return (u16)(r >> 16);
}
__device__ __forceinline__ float bf2f(u16 h) {
  union { unsigned u; float f; } v; v.u = ((unsigned)h) << 16; return v.f;
}
__device__ __forceinline__ u8 f2fp8(float x) {
  __hip_fp8_e4m3 h(x);
  return (u8)h.__x;
}
__device__ __forceinline__ void gld16(const u16* g, u16* l) {
  __builtin_amdgcn_global_load_lds(
      (const __attribute__((address_space(1))) void*)g,
      (__attribute__((address_space(3))) void*)l, 16, 0, 0);
}
__device__ __forceinline__ void gld16b(const u8* g, u8* l) {
  __builtin_amdgcn_global_load_lds(
      (const __attribute__((address_space(1))) void*)g,
      (__attribute__((address_space(3))) void*)l, 16, 0, 0);
}
// bf16 LDS plane rows of 32 u16, 16B granule XOR-swizzled by row&3
__device__ __forceinline__ s16x8 frag32(const u16* plane, int row, int kb) {
  int s = kb ^ (row & 3);
  return *(const s16x8*)(plane + row * 32 + s * 8);
}
__device__ __forceinline__ f32x4 mfma16(s16x8 a, s16x8 b, f32x4 c) {
  return __builtin_amdgcn_mfma_f32_16x16x32_bf16(a, b, c, 0, 0, 0);
}
__device__ __forceinline__ f32x4 mfma8(s64 a, s64 b, f32x4 c) {
  return __builtin_amdgcn_mfma_f32_16x16x32_fp8_fp8(a, b, c, 0, 0, 0);
}

// ---------------- prep kernels ----------------

__global__ __launch_bounds__(256) void k_mean(const float* __restrict__ sx,
                                              float* __restrict__ mean) {
  int d = blockIdx.x * 256 + threadIdx.x;
  float a = 0.f;
  for (int r = 0; r < NS; ++r) a += sx[(size_t)r * D + d];
  mean[d] = a / (float)NS;
}

__global__ __launch_bounds__(256) void k_invn(const float* __restrict__ x,
                                              const float* __restrict__ mean,
                                              float* __restrict__ invn) {
  int r = blockIdx.x;
  int t = threadIdx.x;
  float4 v = ((const float4*)(x + (size_t)r * D))[t];
  float4 m = ((const float4*)mean)[t];
  float a = v.x - m.x, b = v.y - m.y, c = v.z - m.z, d = v.w - m.w;
  float s = a * a + b * b + c * c + d * d;
#pragma unroll
  for (int off = 1; off < 64; off <<= 1) s += __shfl_xor(s, off);
  __shared__ float ws[4];
  if ((t & 63) == 0) ws[t >> 6] = s;
  __syncthreads();
  if (t == 0) invn[r] = 1.0f / sqrtf(ws[0] + ws[1] + ws[2] + ws[3]);
}

__global__ __launch_bounds__(256) void k_supsum(const float* __restrict__ sx,
        const int* __restrict__ sy, const float* __restrict__ mean,
        const float* __restrict__ invs, float* __restrict__ supsum,
        float* __restrict__ supcnt) {
  int c = blockIdx.x;
  int t = threadIdx.x;
  float a0 = 0.f, a1 = 0.f, a2 = 0.f, a3 = 0.f;
  int cnt = 0;
  if (c < C) {
    for (int r = 0; r < NS; ++r) {
      if (sy[r] == c) {
        ++cnt;
        float inv = invs[r];
        a0 += (sx[(size_t)r * D + t      ] - mean[t      ]) * inv;
        a1 += (sx[(size_t)r * D + t + 256] - mean[t + 256]) * inv;
        a2 += (sx[(size_t)r * D + t + 512] - mean[t + 512]) * inv;
        a3 += (sx[(size_t)r * D + t + 768] - mean[t + 768]) * inv;
      }
    }
  }
  supsum[(size_t)c * D + t      ] = a0;
  supsum[(size_t)c * D + t + 256] = a1;
  supsum[(size_t)c * D + t + 512] = a2;
  supsum[(size_t)c * D + t + 768] = a3;
  if (t == 0) supcnt[c] = (float)cnt;
}

__global__ void k_zero(int* __restrict__ corr) {
  if (threadIdx.x == 0) corr[0] = 0;
}

__global__ void k_out(const int* __restrict__ corr, float* __restrict__ out) {
  if (threadIdx.x == 0) out[0] = (float)corr[0] * (1.0f / (float)NQ);
}

// normalize q; write:
//  qfh/qfl: bf16 hi/lo k-blocked fragment planes [(q>>7)*32+ks32][row128][32]
//  qf8:     fp8(16x) pre-fragmented A-plane [tile][kb64][rg8][lane64][16B]
//  qt8:     fp8(16x) transposed [d][NQ]
__global__ __launch_bounds__(256) void k_qsplit(const float* __restrict__ qx,
        const float* __restrict__ mean, const float* __restrict__ invq,
        u16* __restrict__ qfh, u16* __restrict__ qfl,
        u8* __restrict__ qf8, u8* __restrict__ qt8) {
  __shared__ u16 Lh[64][70];
  __shared__ float mloc[64], iloc[64];
  int t = threadIdx.x;
  int q0 = blockIdx.x * 64, d0 = blockIdx.y * 64;
  if (t < 16) ((float4*)mloc)[t] = ((const float4*)(mean + d0))[t];
  else if (t < 32) ((float4*)iloc)[t - 16] = ((const float4*)(invq + q0))[t - 16];
  __syncthreads();
  int r = t >> 2, c0 = (t & 3) * 16;
  float inv = iloc[r];
  const float* src = qx + (size_t)(q0 + r) * D + d0 + c0;
  union { u16 s[16]; uint4 q[2]; } H, L;
  union { u8 b[16]; unsigned long long q[2]; } F;
#pragma unroll
  for (int j = 0; j < 16; j += 4) {
    float4 v = *(const float4*)(src + j);
    float xs[4] = {v.x, v.y, v.z, v.w};
#pragma unroll
    for (int u = 0; u < 4; ++u) {
      float x = (xs[u] - mloc[c0 + j + u]) * inv;
      u16 h = f2bf(x);
      H.s[j + u] = h;
      L.s[j + u] = f2bf(x - bf2f(h));
      F.b[j + u] = f2fp8(16.0f * x);
    }
  }
#pragma unroll
  for (int j = 0; j < 16; j += 2)
    *(ushort2*)&Lh[r][c0 + j] = make_ushort2(H.s[j], H.s[j + 1]);
  // bf16 fragment planes (kblk32)
  {
    int d = d0 + c0;
    int ks = d >> 5;
    int kin = c0 & 16;
    int rowin = (q0 & 64) + r;
    size_t fb = ((size_t)((q0 >> 7) * 32 + ks) * 128 + rowin) * 32 + kin;
    *(uint4*)(qfh + fb)     = H.q[0];
    *(uint4*)(qfh + fb + 8) = H.q[1];
    *(uint4*)(qfl + fb)     = L.q[0];
    *(uint4*)(qfl + fb + 8) = L.q[1];
  }
  // fp8 pre-fragmented A-plane (kblk64): lane = slot*16 + (row&15); 16B = [h0|h1]
  {
    int h8 = (c0 >= 32) ? 1 : 0;
    int sA = (c0 & 31) >> 3;          // 0 or 2
    size_t fb8 = (((size_t)(q0 >> 7) * 16 + (d0 >> 6)) * 8 +
                  ((q0 & 64) >> 4) + (r >> 4)) * 1024;
    int lb = (r & 15) * 16 + h8 * 8;
    *(unsigned long long*)(qf8 + fb8 + sA * 256 + lb)       = F.q[0];
    *(unsigned long long*)(qf8 + fb8 + (sA + 1) * 256 + lb) = F.q[1];
  }
  __syncthreads();
  // transpose 4x4 sub-tiles -> qt8 (fp8 of 16*hi)
  int tq4 = (t & 15) * 4, td4 = (t >> 4) * 4;
  u16 a[4][4];
#pragma unroll
  for (int i = 0; i < 4; ++i) {
    ushort2 p0 = *(const ushort2*)&Lh[tq4 + i][td4];
    ushort2 p1 = *(const ushort2*)&Lh[tq4 + i][td4 + 2];
    a[i][0] = p0.x; a[i][1] = p0.y; a[i][2] = p1.x; a[i][3] = p1.y;
  }
#pragma unroll
  for (int j = 0; j < 4; ++j) {
    uchar4 o;
    o.x = f2fp8(16.0f * bf2f(a[0][j]));
    o.y = f2fp8(16.0f * bf2f(a[1][j]));
    o.z = f2fp8(16.0f * bf2f(a[2][j]));
    o.w = f2fp8(16.0f * bf2f(a[3][j]));
    *(uchar4*)(qt8 + (size_t)(d0 + td4 + j) * NQ + q0 + tq4) = o;
  }
}

// centroid update; INIT=1: den=supcnt, no part/wsump. Writes bf16 planes (for
// final pass), fp8 plane cf8 (16x, granule-swizzled), fp32 c2.
template<int INIT>
__global__ __launch_bounds__(256) void k_updm(const float* __restrict__ supsum,
        const float* __restrict__ part, const float* __restrict__ wsump,
        const float* __restrict__ supcnt,
        u16* __restrict__ cfh, u16* __restrict__ cfl, u8* __restrict__ cf8,
        float* __restrict__ c2) {
  int c = blockIdx.x, t = threadIdx.x;
  __shared__ float red[4];
  float den;
  if (INIT) {
    den = supcnt[c];
  } else {
    float s = 0.f;
    for (int b = t; b < NQ / 128; b += 256) s += wsump[(size_t)b * CP + c];
#pragma unroll
    for (int off = 1; off < 64; off <<= 1) s += __shfl_xor(s, off);
    if ((t & 63) == 0) red[t >> 6] = s;
    __syncthreads();
    den = supcnt[c] + red[0] + red[1] + red[2] + red[3];
    __syncthreads();
  }
  float ss = 0.f;
  float vals[4];
#pragma unroll
  for (int j = 0; j < 4; ++j) {
    int d = t + j * 256;
    float s = supsum[(size_t)c * D + d];
    if (!INIT) {
      float ps = 0.f;
      for (int kc = 0; kc < KC; ++kc) ps += part[((size_t)kc * CP + c) * D + d];
      s += 0.0009765625f * ps;   // / (64*16)
    }
    float v = (c < C) ? s / den : 0.f;
    vals[j] = v; ss += v * v;
  }
#pragma unroll
  for (int j = 0; j < 4; ++j) {
    int d = t + j * 256;
    size_t a16 = (size_t)(d >> 5) * (CP * 32) + c * 32 +
                 ((((d >> 3) & 3) ^ (c & 3)) * 8) + (d & 7);
    u16 h = f2bf(vals[j]);
    cfh[a16] = h;
    cfl[a16] = f2bf(vals[j] - bf2f(h));
    size_t a8 = ((size_t)(d >> 6) * CP + c) * 64 +
                ((((d >> 4) & 3) ^ (c & 3)) * 16) + (d & 15);
    cf8[a8] = f2fp8(16.0f * vals[j]);
  }
#pragma unroll
  for (int off = 1; off < 64; off <<= 1) ss += __shfl_xor(ss, off);
  __syncthreads();
  if ((t & 63) == 0) red[t >> 6] = ss;
  __syncthreads();
  if (t == 0) c2[c] = (c < C) ? (red[0] + red[1] + red[2] + red[3]) : 1e30f;
}

// ---------------- fp8 GEMM1 (iterations): logits + softmax -> Wf8 + col sums ----------------

__global__ __launch_bounds__(256) void k_logits8(
    const u8* __restrict__ qf8, const u8* __restrict__ cf8,
    const float* __restrict__ c2,
    u8* __restrict__ Wf8, float* __restrict__ wsump) {
  __shared__ __align__(16) u8 sm[3 * 7168];
  __shared__ float wred[4][CP];
  int t = threadIdx.x, w = t >> 6, l = t & 63;
  int qblk = blockIdx.x;
  const u8* ap0 = qf8 + (size_t)qblk * 131072 + (size_t)(w * 2) * 1024 + l * 16;
  int s_ = l >> 4, r15 = l & 15;
  int o8 = (s_ & 1) * 8;
  int go0 = s_ >> 1, go1 = 2 + (s_ >> 1);

  f32x4 acc[2][7];
#pragma unroll
  for (int mf = 0; mf < 2; ++mf)
#pragma unroll
    for (int nf = 0; nf < 7; ++nf) acc[mf][nf] = (f32x4){0.f, 0.f, 0.f, 0.f};

  auto stageB = [&](u8* buf, int kb) {
    for (int i = w; i < 7; i += 4)
      gld16b(cf8 + (size_t)kb * 7168 + i * 1024 + l * 16, buf + i * 1024);
  };
  auto computeK = [&](const u8* buf, s64x2 a0, s64x2 a1) {
#pragma unroll
    for (int nf = 0; nf < 7; ++nf) {
      int row = nf * 16 + r15;
      const u8* rp = buf + row * 64;
      int sw = row & 3;
      s64 b0 = *(const s64*)(rp + ((go0 ^ sw) << 4) + o8);
      s64 b1 = *(const s64*)(rp + ((go1 ^ sw) << 4) + o8);
      f32x4 x0 = acc[0][nf], x1 = acc[1][nf];
      x0 = mfma8(a0[0], b0, x0); x0 = mfma8(a0[1], b1, x0);
      x1 = mfma8(a1[0], b0, x1); x1 = mfma8(a1[1], b1, x1);
      acc[0][nf] = x0; acc[1][nf] = x1;
    }
  };
#define WAITC8() { if (w < 3) asm volatile("s_waitcnt vmcnt(4)" ::: "memory"); \
                   else       asm volatile("s_waitcnt vmcnt(3)" ::: "memory"); }

  s64x2 a0A, a1A, a0B, a1B;
  u8 *p0 = sm, *p1 = sm + 7168, *p2 = sm + 14336;
  a0A = *(const s64x2*)ap0; a1A = *(const s64x2*)(ap0 + 1024);
  stageB(p0, 0);
  for (int kp = 0; kp < 8; ++kp) {
    int k = kp * 2;
    { const u8* p = ap0 + (size_t)(k + 1) * 8192;
      a0B = *(const s64x2*)p; a1B = *(const s64x2*)(p + 1024); }
    stageB(p1, k + 1);
    WAITC8();
    __builtin_amdgcn_s_barrier();
    computeK(p0, a0A, a1A);
    if (k + 2 < 16) {
      const u8* p = ap0 + (size_t)(k + 2) * 8192;
      a0A = *(const s64x2*)p; a1A = *(const s64x2*)(p + 1024);
      stageB(p2, k + 2);
      WAITC8();
    } else {
      asm volatile("s_waitcnt vmcnt(0)" ::: "memory");
    }
    __builtin_amdgcn_s_barrier();
    computeK(p1, a0B, a1B);
    u8* tmp = p0; p0 = p2; p2 = p1; p1 = tmp;
  }
  __syncthreads();

  float c2v[7];
#pragma unroll
  for (int nf = 0; nf < 7; ++nf) c2v[nf] = c2[nf * 16 + r15];

  const float LS = 2.0f / 256.0f;
  float wcol[7];
#pragma unroll
  for (int nf = 0; nf < 7; ++nf) wcol[nf] = 0.f;
  u8* Wsh8 = sm;   // [112][128] bytes, granule col-swizzle (qi>>4)^(c&7)
#pragma unroll
  for (int mf = 0; mf < 2; ++mf)
#pragma unroll
    for (int r = 0; r < 4; ++r) {
      float Lg[7], mx = -INFINITY;
#pragma unroll
      for (int nf = 0; nf < 7; ++nf) {
        Lg[nf] = LS * acc[mf][nf][r] - c2v[nf];
        mx = fmaxf(mx, Lg[nf]);
      }
#pragma unroll
      for (int off = 1; off < 16; off <<= 1) mx = fmaxf(mx, __shfl_xor(mx, off));
      float e[7], s = 0.f;
#pragma unroll
      for (int nf = 0; nf < 7; ++nf) { e[nf] = expf(BETA * (Lg[nf] - mx)); s += e[nf]; }
#pragma unroll
      for (int off = 1; off < 16; off <<= 1) s += __shfl_xor(s, off);
      float is = 1.f / s;
      int qi = w * 32 + mf * 16 + (l >> 4) * 4 + r;
#pragma unroll
      for (int nf = 0; nf < 7; ++nf) {
        float wv = e[nf] * is;
        wcol[nf] += wv;
        int cc = nf * 16 + r15;
        Wsh8[cc * 128 + (((qi >> 4) ^ (cc & 7)) << 4) + (qi & 15)] =
            f2fp8(64.0f * wv);
      }
    }
#pragma unroll
  for (int off = 16; off < 64; off <<= 1)
#pragma unroll
    for (int nf = 0; nf < 7; ++nf) wcol[nf] += __shfl_xor(wcol[nf], off);
  if (l < 16)
#pragma unroll
    for (int nf = 0; nf < 7; ++nf) wred[w][nf * 16 + l] = wcol[nf];
  __syncthreads();
  // Wf8 global: [ck][ks(32)][c][64B granule-swz g^(c&3)]
  {
    size_t wb = (size_t)(qblk >> 4) * (32 * 7168);
    int ks0 = (qblk * 2) & 31;
    for (int idx = t; idx < 896; idx += 256) {
      int c = idx >> 3, g = idx & 7;
      uint4 v = *(const uint4*)(Wsh8 + c * 128 + ((g ^ (c & 7)) << 4));
      *(uint4*)(Wf8 + wb + (size_t)(ks0 + (g >> 2)) * 7168 + c * 64 +
                (((g & 3) ^ (c & 3)) << 4)) = v;
    }
  }
  if (t < CP) wsump[(size_t)qblk * CP + t] =
      wred[0][t] + wred[1][t] + wred[2][t] + wred[3][t];
#undef WAITC8
}

// ---------------- fp8 GEMM2: part[ck] = Wf8[:,chunk] @ qt8[:,chunk]^T ----------------

__global__ __launch_bounds__(256) void k_wqm8(
    const u8* __restrict__ Wf8, const u8* __restrict__ qt8,
    float* __restrict__ part) {
  __shared__ __align__(16) u8 sm[3][15360];   // per buf: W[112*64] | Q[128*64]
  int t = threadIdx.x, w = t >> 6, l = t & 63;
  int ck = blockIdx.x;
  int d0 = blockIdx.y * 128;
  size_t wbase = (size_t)ck * (32 * 7168);
  size_t qoff  = (size_t)ck * KROWS;
  int s_ = l >> 4, r15 = l & 15;
  int o8 = (s_ & 1) * 8;
  int go0 = s_ >> 1, go1 = 2 + (s_ >> 1);

  f32x4 acc[7][2];
#pragma unroll
  for (int mf = 0; mf < 7; ++mf)
#pragma unroll
    for (int nf = 0; nf < 2; ++nf) acc[mf][nf] = (f32x4){0.f, 0.f, 0.f, 0.f};

  auto stage = [&](u8* buf, int ks) {
    for (int i = w; i < 7; i += 4)
      gld16b(Wf8 + wbase + (size_t)ks * 7168 + i * 1024 + l * 16, buf + i * 1024);
#pragma unroll
    for (int i2 = w * 2; i2 < w * 2 + 2; ++i2) {
      int row = i2 * 16 + (l >> 2);
      int g = (l & 3) ^ ((l >> 2) & 3);
      gld16b(qt8 + (size_t)(d0 + row) * NQ + qoff + (size_t)ks * 64 + g * 16,
             buf + 7168 + i2 * 1024);
    }
  };
  auto computeK = [&](const u8* buf) {
    const u8* qb = buf + 7168;
    s64 bq00, bq01, bq10, bq11;
    {
      int row = w * 32 + r15;
      const u8* rp = qb + row * 64; int sw = row & 3;
      bq00 = *(const s64*)(rp + ((go0 ^ sw) << 4) + o8);
      bq01 = *(const s64*)(rp + ((go1 ^ sw) << 4) + o8);
    }
    {
      int row = w * 32 + 16 + r15;
      const u8* rp = qb + row * 64; int sw = row & 3;
      bq10 = *(const s64*)(rp + ((go0 ^ sw) << 4) + o8);
      bq11 = *(const s64*)(rp + ((go1 ^ sw) << 4) + o8);
    }
#pragma unroll
    for (int mf = 0; mf < 7; ++mf) {
      int row = mf * 16 + r15;
      const u8* rp = buf + row * 64; int sw = row & 3;
      s64 a0 = *(const s64*)(rp + ((go0 ^ sw) << 4) + o8);
      s64 a1 = *(const s64*)(rp + ((go1 ^ sw) << 4) + o8);
      f32x4 x0 = acc[mf][0], x1 = acc[mf][1];
      x0 = mfma8(a0, bq00, x0); x0 = mfma8(a1, bq01, x0);
      x1 = mfma8(a0, bq10, x1); x1 = mfma8(a1, bq11, x1);
      acc[mf][0] = x0; acc[mf][1] = x1;
    }
  };
#define WAITC4() { if (w < 3) asm volatile("s_waitcnt vmcnt(4)" ::: "memory"); \
                   else       asm volatile("s_waitcnt vmcnt(3)" ::: "memory"); }

  u8 *p0 = sm[0], *p1 = sm[1], *p2 = sm[2];
  stage(p0, 0);
  for (int kp = 0; kp < KS8 / 2; ++kp) {
    int k = kp * 2;
    stage(p1, k + 1);
    WAITC4();
    __builtin_amdgcn_s_barrier();
    computeK(p0);
    if (k + 2 < KS8) {
      stage(p2, k + 2);
      WAITC4();
    } else {
      asm volatile("s_waitcnt vmcnt(0)" ::: "memory");
    }
    __builtin_amdgcn_s_barrier();
    computeK(p1);
    u8* tmp = p0; p0 = p2; p2 = p1; p1 = tmp;
  }
#pragma unroll
  for (int mf = 0; mf < 7; ++mf)
#pragma unroll
    for (int nf = 0; nf < 2; ++nf)
#pragma unroll
      for (int r = 0; r < 4; ++r) {
        int c = mf * 16 + (l >> 4) * 4 + r;
        int dg = d0 + w * 32 + nf * 16 + r15;
        part[((size_t)ck * CP + c) * D + dg] = acc[mf][nf][r];
      }
#undef WAITC4
}

// ---------------- final pass: bf16 3-term logits + argmax (proven path) ----------------

template<int FINAL>
__global__ __launch_bounds__(256) void k_logits(
    const u16* __restrict__ qfh, const u16* __restrict__ qfl,
    const u16* __restrict__ cfh, const u16* __restrict__ cfl,
    const float* __restrict__ c2,
    const int* __restrict__ qy, int* __restrict__ corr) {
  __shared__ __align__(16) u16 sm[3 * 7168];
  int t = threadIdx.x, w = t >> 6, l = t & 63;
  int qblk = blockIdx.x;
  size_t abase = (size_t)qblk * 32 * 128 * 32;
  int aoff = (w * 32 + (l & 15)) * 32 + (l >> 4) * 8;
  int kb = l >> 4;

  f32x4 acc[2][7];
#pragma unroll
  for (int mf = 0; mf < 2; ++mf)
#pragma unroll
    for (int nf = 0; nf < 7; ++nf) acc[mf][nf] = (f32x4){0.f, 0.f, 0.f, 0.f};

#define ALOADQ(ks, H0, H1, L0, L1) { \
    const u16* ap_ = qfh + abase + (size_t)(ks) * 4096 + aoff; \
    H0 = *(const s16x8*)ap_;  H1 = *(const s16x8*)(ap_ + 512); \
    const u16* lp_ = qfl + abase + (size_t)(ks) * 4096 + aoff; \
    L0 = *(const s16x8*)lp_;  L1 = *(const s16x8*)(lp_ + 512); }

  auto stageB = [&](u16* buf, int ks) {
    for (int i = w; i < 14; i += 4) {
      const u16* src = (i < 7) ? (cfh + (size_t)(ks) * 3584 + i * 512 + l * 8)
                               : (cfl + (size_t)(ks) * 3584 + (i - 7) * 512 + l * 8);
      gld16(src, buf + i * 512);
    }
  };
  auto computeK = [&](const u16* buf, s16x8 h0, s16x8 h1, s16x8 l0, s16x8 l1) {
#pragma unroll
    for (int nf = 0; nf < 7; ++nf) {
      int row = nf * 16 + (l & 15);
      s16x8 bh = frag32(buf, row, kb);
      s16x8 bl = frag32(buf + 3584, row, kb);
      f32x4 a0 = acc[0][nf], a1 = acc[1][nf];
      a0 = mfma16(l0, bh, a0); a0 = mfma16(h0, bl, a0); a0 = mfma16(h0, bh, a0);
      a1 = mfma16(l1, bh, a1); a1 = mfma16(h1, bl, a1); a1 = mfma16(h1, bh, a1);
      acc[0][nf] = a0; acc[1][nf] = a1;
    }
  };
#define WAITCF() { if (w < 2) asm volatile("s_waitcnt vmcnt(8)" ::: "memory"); \
                   else       asm volatile("s_waitcnt vmcnt(7)" ::: "memory"); }

  s16x8 h0A = {}, h1A = {}, l0A = {}, l1A = {};
  s16x8 h0B = {}, h1B = {}, l0B = {}, l1B = {};
  u16 *p0 = sm, *p1 = sm + 7168, *p2 = sm + 14336;
  ALOADQ(0, h0A, h1A, l0A, l1A);
  stageB(p0, 0);
  for (int kp = 0; kp < 16; ++kp) {
    int k = kp * 2;
    ALOADQ(k + 1, h0B, h1B, l0B, l1B);
    stageB(p1, k + 1);
    WAITCF();
    __builtin_amdgcn_s_barrier();
    computeK(p0, h0A, h1A, l0A, l1A);
    if (k + 2 < 32) {
      ALOADQ(k + 2, h0A, h1A, l0A, l1A);
      stageB(p2, k + 2);
      WAITCF();
    } else {
      asm volatile("s_waitcnt vmcnt(0)" ::: "memory");
    }
    __builtin_amdgcn_s_barrier();
    computeK(p1, h0B, h1B, l0B, l1B);
    u16* tmp = p0; p0 = p2; p2 = p1; p1 = tmp;
  }
  __syncthreads();

  float c2v[7];
#pragma unroll
  for (int nf = 0; nf < 7; ++nf) c2v[nf] = c2[nf * 16 + (l & 15)];

  int cnt = 0;
#pragma unroll
  for (int mf = 0; mf < 2; ++mf)
#pragma unroll
    for (int r = 0; r < 4; ++r) {
      float bv = -INFINITY; int bi = 0x7fffffff;
#pragma unroll
      for (int nf = 0; nf < 7; ++nf) {
        float Lg = 2.f * acc[mf][nf][r] - c2v[nf];
        int cc = nf * 16 + (l & 15);
        if (Lg > bv || (Lg == bv && cc < bi)) { bv = Lg; bi = cc; }
      }
#pragma unroll
      for (int off = 1; off < 16; off <<= 1) {
        float ov = __shfl_xor(bv, off); int oi = __shfl_xor(bi, off);
        if (ov > bv || (ov == bv && oi < bi)) { bv = ov; bi = oi; }
      }
      if ((l & 15) == 0) {
        int qi = w * 32 + mf * 16 + (l >> 4) * 4 + r;
        cnt += (bi == qy[blockIdx.x * 128 + qi]) ? 1 : 0;
      }
    }
  if ((l & 15) == 0) atomicAdd(corr, cnt);
#undef ALOADQ
#undef WAITCF
}

// ---------------- launch ----------------

extern "C" void kernel_launch(void* const* d_in, const int* in_sizes, int n_in,
                              void* d_out, int out_size, void* d_ws, size_t ws_size,
                              hipStream_t stream) {
  const float* sx = (const float*)d_in[0];
  const int*   sy = (const int*)d_in[1];
  const float* qx = (const float*)d_in[2];
  const int*   qy = (const int*)d_in[3];

  char* base = (char*)d_ws;
  size_t o = 0;
  auto take = [&](size_t bytes) { size_t r = o; o += (bytes + 511) & ~(size_t)511; return r; };
  float* mean   = (float*)(base + take(4096));
  float* invs   = (float*)(base + take(4096));
  float* invq   = (float*)(base + take((size_t)NQ * 4));
  float* supsum = (float*)(base + take((size_t)CP * D * 4));
  float* supcnt = (float*)(base + take(512));
  float* c2A    = (float*)(base + take(512));
  float* c2B    = (float*)(base + take(512));
  float* wsump  = (float*)(base + take((size_t)(NQ / 128) * CP * 4));
  int*   corr   = (int*)(base + take(512));
  u16* cfhA = (u16*)(base + take((size_t)CP * D * 2));
  u16* cflA = (u16*)(base + take((size_t)CP * D * 2));
  u16* cfhB = (u16*)(base + take((size_t)CP * D * 2));
  u16* cflB = (u16*)(base + take((size_t)CP * D * 2));
  u8*  cf8A = (u8*)(base + take((size_t)CP * D));
  u8*  cf8B = (u8*)(base + take((size_t)CP * D));
  u8*  Wf8  = (u8*)(base + take((size_t)CP * NQ));
  float* part = (float*)(base + take((size_t)KC * CP * D * 4));
  u16* qfh  = (u16*)(base + take((size_t)NQ * D * 2));
  u16* qfl  = (u16*)(base + take((size_t)NQ * D * 2));
  u8*  qf8  = (u8*)(base + take((size_t)NQ * D));
  u8*  qt8  = (u8*)(base + take((size_t)NQ * D));
  size_t fast_need = o;

  if (ws_size < fast_need) {
    k_zero<<<1, 64, 0, stream>>>((int*)d_out);
    return;
  }

  k_mean<<<dim3(D / 256), 256, 0, stream>>>(sx, mean);
  k_invn<<<dim3(NS), 256, 0, stream>>>(sx, mean, invs);
  k_invn<<<dim3(NQ), 256, 0, stream>>>(qx, mean, invq);
  k_supsum<<<dim3(CP), 256, 0, stream>>>(sx, sy, mean, invs, supsum, supcnt);
  k_updm<1><<<dim3(CP), 256, 0, stream>>>(supsum, part, wsump, supcnt,
                                          cfhA, cflA, cf8A, c2A);
  k_qsplit<<<dim3(NQ / 64, D / 64), 256, 0, stream>>>(qx, mean, invq,
                                                      qfh, qfl, qf8, qt8);

  u16 *chc = cfhA, *clc = cflA, *chn = cfhB, *cln = cflB;
  u8  *c8c = cf8A, *c8n = cf8B;
  float *c2c = c2A, *c2n = c2B;
  for (int it = 0; it < NITER; ++it) {
    k_logits8<<<dim3(NQ / 128), 256, 0, stream>>>(qf8, c8c, c2c, Wf8, wsump);
    k_wqm8<<<dim3(KC, D / 128), 256, 0, stream>>>(Wf8, qt8, part);
    k_updm<0><<<dim3(CP), 256, 0, stream>>>(supsum, part, wsump, supcnt,
                                            chn, cln, c8n, c2n);
    u16* tu;
    tu = chc; chc = chn; chn = tu;
    tu = clc; clc = cln; cln = tu;
    u8* t8 = c8c; c8c = c8n; c8n = t8;
    float* tf = c2c; c2c = c2n; c2n = tf;
  }
  k_zero<<<1, 64, 0, stream>>>(corr);
  k_logits<1><<<dim3(NQ / 128), 256, 0, stream>>>(qfh, qfl, chc, clc, c2c,
                                                  qy, corr);
  k_out<<<1, 64, 0, stream>>>(corr, (float*)d_out);
}

// Round 7
// 1612.662 us; speedup vs baseline: 2.4394x; 1.1131x over previous
//
#include <hip/hip_runtime.h>
#include <hip/hip_fp8.h>
#include <math.h>

#define NS 1000
#define NQ 131072
#define D  1024
#define C  100
#define CP 112          // padded class count (16*7)
#define BETA 5.0f
#define NITER 10
#define KC 64           // split-K chunks for W^T q
#define KROWS (NQ/KC)   // 2048 q per chunk
#define KS8 (KROWS/64)  // 32 fp8 k-steps per chunk

typedef float f32x4 __attribute__((ext_vector_type(4)));
typedef short s16x8 __attribute__((ext_vector_type(8)));
typedef long s64;
typedef s64 s64x2 __attribute__((ext_vector_type(2)));
typedef unsigned short u16;
typedef unsigned char u8;
typedef unsigned long long ull;

__device__ __forceinline__ u16 f2bf(float x) {
  union { float f; unsigned u; } v; v.f = x;
  unsigned r = v.u + 0x7fffu + ((v.u >> 16) & 1u);
  return (u16)(r >> 16);
}
__device__ __forceinline__ float bf2f(u16 h) {
  union { unsigned u; float f; } v; v.u = ((unsigned)h) << 16; return v.f;
}
__device__ __forceinline__ u8 f2fp8(float x) {
  __hip_fp8_e4m3 h(x);
  return (u8)h.__x;
}
__device__ __forceinline__ void gld16(const u16* g, u16* l) {
  __builtin_amdgcn_global_load_lds(
      (const __attribute__((address_space(1))) void*)g,
      (__attribute__((address_space(3))) void*)l, 16, 0, 0);
}
__device__ __forceinline__ void gld16b(const u8* g, u8* l) {
  __builtin_amdgcn_global_load_lds(
      (const __attribute__((address_space(1))) void*)g,
      (__attribute__((address_space(3))) void*)l, 16, 0, 0);
}
// bf16 LDS plane rows of 32 u16, 16B granule XOR-swizzled by row&3
__device__ __forceinline__ s16x8 frag32(const u16* plane, int row, int kb) {
  int s = kb ^ (row & 3);
  return *(const s16x8*)(plane + row * 32 + s * 8);
}
__device__ __forceinline__ f32x4 mfma16(s16x8 a, s16x8 b, f32x4 c) {
  return __builtin_amdgcn_mfma_f32_16x16x32_bf16(a, b, c, 0, 0, 0);
}
__device__ __forceinline__ f32x4 mfma8(s64 a, s64 b, f32x4 c) {
  return __builtin_amdgcn_mfma_f32_16x16x32_fp8_fp8(a, b, c, 0, 0, 0);
}

// ---------------- prep kernels ----------------

__global__ __launch_bounds__(256) void k_mean(const float* __restrict__ sx,
                                              float* __restrict__ mean) {
  int d = blockIdx.x * 256 + threadIdx.x;
  float a = 0.f;
  for (int r = 0; r < NS; ++r) a += sx[(size_t)r * D + d];
  mean[d] = a / (float)NS;
}

__global__ __launch_bounds__(256) void k_invn(const float* __restrict__ x,
                                              const float* __restrict__ mean,
                                              float* __restrict__ invn) {
  int r = blockIdx.x;
  int t = threadIdx.x;
  float4 v = ((const float4*)(x + (size_t)r * D))[t];
  float4 m = ((const float4*)mean)[t];
  float a = v.x - m.x, b = v.y - m.y, c = v.z - m.z, d = v.w - m.w;
  float s = a * a + b * b + c * c + d * d;
#pragma unroll
  for (int off = 1; off < 64; off <<= 1) s += __shfl_xor(s, off);
  __shared__ float ws[4];
  if ((t & 63) == 0) ws[t >> 6] = s;
  __syncthreads();
  if (t == 0) invn[r] = 1.0f / sqrtf(ws[0] + ws[1] + ws[2] + ws[3]);
}

__global__ __launch_bounds__(256) void k_supsum(const float* __restrict__ sx,
        const int* __restrict__ sy, const float* __restrict__ mean,
        const float* __restrict__ invs, float* __restrict__ supsum,
        float* __restrict__ supcnt) {
  int c = blockIdx.x;
  int t = threadIdx.x;
  float a0 = 0.f, a1 = 0.f, a2 = 0.f, a3 = 0.f;
  int cnt = 0;
  if (c < C) {
    for (int r = 0; r < NS; ++r) {
      if (sy[r] == c) {
        ++cnt;
        float inv = invs[r];
        a0 += (sx[(size_t)r * D + t      ] - mean[t      ]) * inv;
        a1 += (sx[(size_t)r * D + t + 256] - mean[t + 256]) * inv;
        a2 += (sx[(size_t)r * D + t + 512] - mean[t + 512]) * inv;
        a3 += (sx[(size_t)r * D + t + 768] - mean[t + 768]) * inv;
      }
    }
  }
  supsum[(size_t)c * D + t      ] = a0;
  supsum[(size_t)c * D + t + 256] = a1;
  supsum[(size_t)c * D + t + 512] = a2;
  supsum[(size_t)c * D + t + 768] = a3;
  if (t == 0) supcnt[c] = (float)cnt;
}

__global__ void k_zero(int* __restrict__ corr) {
  if (threadIdx.x == 0) corr[0] = 0;
}

__global__ void k_out(const int* __restrict__ corr, float* __restrict__ out) {
  if (threadIdx.x == 0) out[0] = (float)corr[0] * (1.0f / (float)NQ);
}

// fused: row norms (invq) + fp8 planes qf8 (fragment layout) + qt8 (transposed)
// grid: NQ/64 blocks x 256 threads
__global__ __launch_bounds__(256) void k_qprep(const float* __restrict__ qx,
        const float* __restrict__ mean, float* __restrict__ invq,
        u8* __restrict__ qf8, u8* __restrict__ qt8) {
  __shared__ float msh[1024];
  __shared__ float pp[64];
  __shared__ float invql[64];
  __shared__ u8 T8[64 * 68];
  int t = threadIdx.x, w = t >> 6, l = t & 63;
  int q0 = blockIdx.x * 64;
  ((float4*)msh)[t] = ((const float4*)mean)[t];
  __syncthreads();

  // phase 1: row sum-of-squares, coalesced; wave w owns rows w*16..w*16+15
#pragma unroll 1
  for (int rr = 0; rr < 16; ++rr) {
    int row = w * 16 + rr;
    const float* rp = qx + (size_t)(q0 + row) * D;
    float s = 0.f;
#pragma unroll
    for (int seg = 0; seg < 4; ++seg) {
      float4 v = *(const float4*)(rp + seg * 256 + l * 4);
      float4 m = *(const float4*)(msh + seg * 256 + l * 4);
      float a = v.x - m.x, b = v.y - m.y, c = v.z - m.z, d = v.w - m.w;
      s += a * a + b * b + c * c + d * d;
    }
#pragma unroll
    for (int off = 1; off < 64; off <<= 1) s += __shfl_xor(s, off);
    if (l == 0) pp[row] = s;
  }
  __syncthreads();
  if (t < 64) {
    float iv = 1.0f / sqrtf(pp[t]);
    invql[t] = iv;
    invq[q0 + t] = iv;
  }
  __syncthreads();

  // phase 2: convert (re-read via L2), write qf8 fragments + qt8 transpose
  int r = t >> 2, c0 = (t & 3) * 16;
  float iv = invql[r];
  int h8 = (c0 >= 32) ? 1 : 0;
  int sA = (c0 & 31) >> 3;   // 0 or 2
  int lb = (r & 15) * 16 + h8 * 8;
  int tq4 = (t & 15) * 4, td4 = (t >> 4) * 4;
  for (int d0 = 0; d0 < D; d0 += 64) {
    const float* src = qx + (size_t)(q0 + r) * D + d0 + c0;
    union { u8 b[16]; ull q[2]; } F;
#pragma unroll
    for (int j = 0; j < 16; j += 4) {
      float4 v = *(const float4*)(src + j);
      float xs[4] = {v.x, v.y, v.z, v.w};
#pragma unroll
      for (int u = 0; u < 4; ++u) {
        float x = (xs[u] - msh[d0 + c0 + j + u]) * iv;
        F.b[j + u] = f2fp8(16.0f * x);
      }
    }
    // qf8 fragment plane (same layout as proven round-6 k_qsplit)
    size_t fb8 = (((size_t)(q0 >> 7) * 16 + (d0 >> 6)) * 8 +
                  ((q0 & 64) >> 4) + (r >> 4)) * 1024;
    *(ull*)(qf8 + fb8 + sA * 256 + lb)       = F.q[0];
    *(ull*)(qf8 + fb8 + (sA + 1) * 256 + lb) = F.q[1];
    // LDS transpose tile, pitch 68 (uchar4 granularity, <=2-way conflicts)
    __syncthreads();
#pragma unroll
    for (int j = 0; j < 4; ++j)
      *(uchar4*)(T8 + r * 68 + c0 + j * 4) =
          make_uchar4(F.b[j * 4], F.b[j * 4 + 1], F.b[j * 4 + 2], F.b[j * 4 + 3]);
    __syncthreads();
    u8 a[4][4];
#pragma unroll
    for (int i = 0; i < 4; ++i)
      *(uchar4*)a[i] = *(const uchar4*)(T8 + (tq4 + i) * 68 + td4);
#pragma unroll
    for (int j = 0; j < 4; ++j)
      *(uchar4*)(qt8 + (size_t)(d0 + td4 + j) * NQ + q0 + tq4) =
          make_uchar4(a[0][j], a[1][j], a[2][j], a[3][j]);
  }
}

// centroid update; grid (CP, 4), one d-element per thread.
// c2 emitted as 4 deterministic partials c2p[c*4+by] (consumers sum in order).
template<int INIT>
__global__ __launch_bounds__(256) void k_updm(const float* __restrict__ supsum,
        const float* __restrict__ part, const float* __restrict__ wsump,
        const float* __restrict__ supcnt,
        u16* __restrict__ cfh, u16* __restrict__ cfl, u8* __restrict__ cf8,
        float* __restrict__ c2p) {
  int c = blockIdx.x, by = blockIdx.y, t = threadIdx.x;
  __shared__ float red[4];
  float den;
  if (INIT) {
    den = supcnt[c];
  } else {
    float s = 0.f;
#pragma unroll
    for (int b = 0; b < 4; ++b) s += wsump[(size_t)(t + b * 256) * CP + c];
#pragma unroll
    for (int off = 1; off < 64; off <<= 1) s += __shfl_xor(s, off);
    if ((t & 63) == 0) red[t >> 6] = s;
    __syncthreads();
    den = supcnt[c] + ((red[0] + red[1]) + (red[2] + red[3]));
    __syncthreads();
  }
  int d = by * 256 + t;
  float s = supsum[(size_t)c * D + d];
  if (!INIT) {
    float p0 = 0.f, p1 = 0.f, p2 = 0.f, p3 = 0.f;
    for (int kc = 0; kc < KC; kc += 4) {
      p0 += part[((size_t)(kc + 0) * CP + c) * D + d];
      p1 += part[((size_t)(kc + 1) * CP + c) * D + d];
      p2 += part[((size_t)(kc + 2) * CP + c) * D + d];
      p3 += part[((size_t)(kc + 3) * CP + c) * D + d];
    }
    s += 0.0009765625f * ((p0 + p1) + (p2 + p3));   // /(64*16)
  }
  float v = (c < C) ? s / den : 0.f;
  size_t a16 = (size_t)(d >> 5) * (CP * 32) + c * 32 +
               ((((d >> 3) & 3) ^ (c & 3)) * 8) + (d & 7);
  u16 h = f2bf(v);
  cfh[a16] = h;
  cfl[a16] = f2bf(v - bf2f(h));
  size_t a8 = ((size_t)(d >> 6) * CP + c) * 64 +
              ((((d >> 4) & 3) ^ (c & 3)) * 16) + (d & 15);
  cf8[a8] = f2fp8(16.0f * v);
  float ss = v * v;
#pragma unroll
  for (int off = 1; off < 64; off <<= 1) ss += __shfl_xor(ss, off);
  __syncthreads();
  if ((t & 63) == 0) red[t >> 6] = ss;
  __syncthreads();
  if (t == 0) c2p[c * 4 + by] =
      (c < C) ? ((red[0] + red[1]) + (red[2] + red[3])) : 2.5e29f;
}

// ---------------- fp8 GEMM1 (iterations): logits + softmax -> Wf8 + col sums ----------------

__global__ __launch_bounds__(256) void k_logits8(
    const u8* __restrict__ qf8, const u8* __restrict__ cf8,
    const float* __restrict__ c2p,
    u8* __restrict__ Wf8, float* __restrict__ wsump) {
  __shared__ __align__(16) u8 sm[3 * 7168];
  __shared__ float wred[4][CP];
  int t = threadIdx.x, w = t >> 6, l = t & 63;
  int qblk = blockIdx.x;
  const u8* ap0 = qf8 + (size_t)qblk * 131072 + (size_t)(w * 2) * 1024 + l * 16;
  int s_ = l >> 4, r15 = l & 15;
  int o8 = (s_ & 1) * 8;
  int go0 = s_ >> 1, go1 = 2 + (s_ >> 1);

  f32x4 acc[2][7];
#pragma unroll
  for (int mf = 0; mf < 2; ++mf)
#pragma unroll
    for (int nf = 0; nf < 7; ++nf) acc[mf][nf] = (f32x4){0.f, 0.f, 0.f, 0.f};

  auto stageB = [&](u8* buf, int kb) {
    for (int i = w; i < 7; i += 4)
      gld16b(cf8 + (size_t)kb * 7168 + i * 1024 + l * 16, buf + i * 1024);
  };
  auto computeK = [&](const u8* buf, s64x2 a0, s64x2 a1) {
#pragma unroll
    for (int nf = 0; nf < 7; ++nf) {
      int row = nf * 16 + r15;
      const u8* rp = buf + row * 64;
      int sw = row & 3;
      s64 b0 = *(const s64*)(rp + ((go0 ^ sw) << 4) + o8);
      s64 b1 = *(const s64*)(rp + ((go1 ^ sw) << 4) + o8);
      f32x4 x0 = acc[0][nf], x1 = acc[1][nf];
      x0 = mfma8(a0[0], b0, x0); x0 = mfma8(a0[1], b1, x0);
      x1 = mfma8(a1[0], b0, x1); x1 = mfma8(a1[1], b1, x1);
      acc[0][nf] = x0; acc[1][nf] = x1;
    }
  };
#define WAITC8() { if (w < 3) asm volatile("s_waitcnt vmcnt(4)" ::: "memory"); \
                   else       asm volatile("s_waitcnt vmcnt(3)" ::: "memory"); }

  s64x2 a0A, a1A, a0B, a1B;
  u8 *p0 = sm, *p1 = sm + 7168, *p2 = sm + 14336;
  a0A = *(const s64x2*)ap0; a1A = *(const s64x2*)(ap0 + 1024);
  stageB(p0, 0);
  for (int kp = 0; kp < 8; ++kp) {
    int k = kp * 2;
    { const u8* p = ap0 + (size_t)(k + 1) * 8192;
      a0B = *(const s64x2*)p; a1B = *(const s64x2*)(p + 1024); }
    stageB(p1, k + 1);
    WAITC8();
    __builtin_amdgcn_s_barrier();
    computeK(p0, a0A, a1A);
    if (k + 2 < 16) {
      const u8* p = ap0 + (size_t)(k + 2) * 8192;
      a0A = *(const s64x2*)p; a1A = *(const s64x2*)(p + 1024);
      stageB(p2, k + 2);
      WAITC8();
    } else {
      asm volatile("s_waitcnt vmcnt(0)" ::: "memory");
    }
    __builtin_amdgcn_s_barrier();
    computeK(p1, a0B, a1B);
    u8* tmp = p0; p0 = p2; p2 = p1; p1 = tmp;
  }
  __syncthreads();

  float c2v[7];
#pragma unroll
  for (int nf = 0; nf < 7; ++nf) {
    int cc = nf * 16 + r15;
    float4 p = *(const float4*)(c2p + cc * 4);
    c2v[nf] = (p.x + p.y) + (p.z + p.w);
  }

  const float LS = 2.0f / 256.0f;
  float wcol[7];
#pragma unroll
  for (int nf = 0; nf < 7; ++nf) wcol[nf] = 0.f;
  u8* Wsh8 = sm;   // [112][128] bytes, granule col-swizzle (qi>>4)^(c&7)
#pragma unroll
  for (int mf = 0; mf < 2; ++mf)
#pragma unroll
    for (int r = 0; r < 4; ++r) {
      float Lg[7], mx = -INFINITY;
#pragma unroll
      for (int nf = 0; nf < 7; ++nf) {
        Lg[nf] = LS * acc[mf][nf][r] - c2v[nf];
        mx = fmaxf(mx, Lg[nf]);
      }
#pragma unroll
      for (int off = 1; off < 16; off <<= 1) mx = fmaxf(mx, __shfl_xor(mx, off));
      float e[7], s = 0.f;
#pragma unroll
      for (int nf = 0; nf < 7; ++nf) { e[nf] = expf(BETA * (Lg[nf] - mx)); s += e[nf]; }
#pragma unroll
      for (int off = 1; off < 16; off <<= 1) s += __shfl_xor(s, off);
      float is = 1.f / s;
      int qi = w * 32 + mf * 16 + (l >> 4) * 4 + r;
#pragma unroll
      for (int nf = 0; nf < 7; ++nf) {
        float wv = e[nf] * is;
        wcol[nf] += wv;
        int cc = nf * 16 + r15;
        Wsh8[cc * 128 + (((qi >> 4) ^ (cc & 7)) << 4) + (qi & 15)] =
            f2fp8(64.0f * wv);
      }
    }
#pragma unroll
  for (int off = 16; off < 64; off <<= 1)
#pragma unroll
    for (int nf = 0; nf < 7; ++nf) wcol[nf] += __shfl_xor(wcol[nf], off);
  if (l < 16)
#pragma unroll
    for (int nf = 0; nf < 7; ++nf) wred[w][nf * 16 + l] = wcol[nf];
  __syncthreads();
  // Wf8 global: [ck][ks(32)][c][64B granule-swz g^(c&3)]
  {
    size_t wb = (size_t)(qblk >> 4) * (32 * 7168);
    int ks0 = (qblk * 2) & 31;
    for (int idx = t; idx < 896; idx += 256) {
      int c = idx >> 3, g = idx & 7;
      uint4 v = *(const uint4*)(Wsh8 + c * 128 + ((g ^ (c & 7)) << 4));
      *(uint4*)(Wf8 + wb + (size_t)(ks0 + (g >> 2)) * 7168 + c * 64 +
                (((g & 3) ^ (c & 3)) << 4)) = v;
    }
  }
  if (t < CP) wsump[(size_t)qblk * CP + t] =
      wred[0][t] + wred[1][t] + wred[2][t] + wred[3][t];
#undef WAITC8
}

// ---------------- fp8 GEMM2: part[ck] = Wf8[:,chunk] @ qt8[:,chunk]^T ----------------

__global__ __launch_bounds__(256) void k_wqm8(
    const u8* __restrict__ Wf8, const u8* __restrict__ qt8,
    float* __restrict__ part) {
  __shared__ __align__(16) u8 sm[3][15360];   // per buf: W[112*64] | Q[128*64]
  int t = threadIdx.x, w = t >> 6, l = t & 63;
  int ck = blockIdx.x;
  int d0 = blockIdx.y * 128;
  size_t wbase = (size_t)ck * (32 * 7168);
  size_t qoff  = (size_t)ck * KROWS;
  int s_ = l >> 4, r15 = l & 15;
  int o8 = (s_ & 1) * 8;
  int go0 = s_ >> 1, go1 = 2 + (s_ >> 1);

  f32x4 acc[7][2];
#pragma unroll
  for (int mf = 0; mf < 7; ++mf)
#pragma unroll
    for (int nf = 0; nf < 2; ++nf) acc[mf][nf] = (f32x4){0.f, 0.f, 0.f, 0.f};

  auto stage = [&](u8* buf, int ks) {
    for (int i = w; i < 7; i += 4)
      gld16b(Wf8 + wbase + (size_t)ks * 7168 + i * 1024 + l * 16, buf + i * 1024);
#pragma unroll
    for (int i2 = w * 2; i2 < w * 2 + 2; ++i2) {
      int row = i2 * 16 + (l >> 2);
      int g = (l & 3) ^ ((l >> 2) & 3);
      gld16b(qt8 + (size_t)(d0 + row) * NQ + qoff + (size_t)ks * 64 + g * 16,
             buf + 7168 + i2 * 1024);
    }
  };
  auto computeK = [&](const u8* buf) {
    const u8* qb = buf + 7168;
    s64 bq00, bq01, bq10, bq11;
    {
      int row = w * 32 + r15;
      const u8* rp = qb + row * 64; int sw = row & 3;
      bq00 = *(const s64*)(rp + ((go0 ^ sw) << 4) + o8);
      bq01 = *(const s64*)(rp + ((go1 ^ sw) << 4) + o8);
    }
    {
      int row = w * 32 + 16 + r15;
      const u8* rp = qb + row * 64; int sw = row & 3;
      bq10 = *(const s64*)(rp + ((go0 ^ sw) << 4) + o8);
      bq11 = *(const s64*)(rp + ((go1 ^ sw) << 4) + o8);
    }
#pragma unroll
    for (int mf = 0; mf < 7; ++mf) {
      int row = mf * 16 + r15;
      const u8* rp = buf + row * 64; int sw = row & 3;
      s64 a0 = *(const s64*)(rp + ((go0 ^ sw) << 4) + o8);
      s64 a1 = *(const s64*)(rp + ((go1 ^ sw) << 4) + o8);
      f32x4 x0 = acc[mf][0], x1 = acc[mf][1];
      x0 = mfma8(a0, bq00, x0); x0 = mfma8(a1, bq01, x0);
      x1 = mfma8(a0, bq10, x1); x1 = mfma8(a1, bq11, x1);
      acc[mf][0] = x0; acc[mf][1] = x1;
    }
  };
#define WAITC4() { if (w < 3) asm volatile("s_waitcnt vmcnt(4)" ::: "memory"); \
                   else       asm volatile("s_waitcnt vmcnt(3)" ::: "memory"); }

  u8 *p0 = sm[0], *p1 = sm[1], *p2 = sm[2];
  stage(p0, 0);
  for (int kp = 0; kp < KS8 / 2; ++kp) {
    int k = kp * 2;
    stage(p1, k + 1);
    WAITC4();
    __builtin_amdgcn_s_barrier();
    computeK(p0);
    if (k + 2 < KS8) {
      stage(p2, k + 2);
      WAITC4();
    } else {
      asm volatile("s_waitcnt vmcnt(0)" ::: "memory");
    }
    __builtin_amdgcn_s_barrier();
    computeK(p1);
    u8* tmp = p0; p0 = p2; p2 = p1; p1 = tmp;
  }
#pragma unroll
  for (int mf = 0; mf < 7; ++mf)
#pragma unroll
    for (int nf = 0; nf < 2; ++nf)
#pragma unroll
      for (int r = 0; r < 4; ++r) {
        int c = mf * 16 + (l >> 4) * 4 + r;
        int dg = d0 + w * 32 + nf * 16 + r15;
        part[((size_t)ck * CP + c) * D + dg] = acc[mf][nf][r];
      }
#undef WAITC4
}

// ---------------- final pass: 3-term bf16 logits from raw qx + argmax ----------------

__global__ __launch_bounds__(256) void k_final(
    const float* __restrict__ qx, const float* __restrict__ mean,
    const float* __restrict__ invq,
    const u16* __restrict__ cfh, const u16* __restrict__ cfl,
    const float* __restrict__ c2p,
    const int* __restrict__ qy, int* __restrict__ corr) {
  __shared__ __align__(16) u16 sm[3 * 7168];
  __shared__ float msh[1024];
  __shared__ float ivsh[128];
  int t = threadIdx.x, w = t >> 6, l = t & 63;
  int q0 = blockIdx.x * 128;
  ((float4*)msh)[t] = ((const float4*)mean)[t];
  if (t < 32) ((float4*)ivsh)[t] = ((const float4*)(invq + q0))[t];
  __syncthreads();

  int r15 = l & 15;
  int ko = (l >> 4) * 8;
  int row0 = w * 32 + r15, row1 = row0 + 16;
  const float* a0p = qx + (size_t)(q0 + row0) * D + ko;
  const float* a1p = qx + (size_t)(q0 + row1) * D + ko;
  float iv0 = ivsh[row0], iv1 = ivsh[row1];
  int kb = l >> 4;

  f32x4 acc[2][7];
#pragma unroll
  for (int mf = 0; mf < 2; ++mf)
#pragma unroll
    for (int nf = 0; nf < 7; ++nf) acc[mf][nf] = (f32x4){0.f, 0.f, 0.f, 0.f};

#define ALOADR(ks, R) { \
    const float* p0_ = a0p + (size_t)(ks) * 32; \
    const float* p1_ = a1p + (size_t)(ks) * 32; \
    R[0] = *(const float4*)p0_; R[1] = *(const float4*)(p0_ + 4); \
    R[2] = *(const float4*)p1_; R[3] = *(const float4*)(p1_ + 4); }

  auto stageB = [&](u16* buf, int ks) {
    for (int i = w; i < 14; i += 4) {
      const u16* src = (i < 7) ? (cfh + (size_t)(ks) * 3584 + i * 512 + l * 8)
                               : (cfl + (size_t)(ks) * 3584 + (i - 7) * 512 + l * 8);
      gld16(src, buf + i * 512);
    }
  };
  auto mk = [&](const float4& u0, const float4& u1, float iv, int ks,
                s16x8& hh, s16x8& ll) {
    float xs[8] = {u0.x, u0.y, u0.z, u0.w, u1.x, u1.y, u1.z, u1.w};
#pragma unroll
    for (int u = 0; u < 8; ++u) {
      float x = (xs[u] - msh[ks * 32 + ko + u]) * iv;
      u16 h = f2bf(x);
      hh[u] = (short)h;
      ll[u] = (short)f2bf(x - bf2f(h));
    }
  };
  auto computeK = [&](const u16* buf, float4* R, int ks) {
    s16x8 h0, l0, h1, l1;
    mk(R[0], R[1], iv0, ks, h0, l0);
    mk(R[2], R[3], iv1, ks, h1, l1);
#pragma unroll
    for (int nf = 0; nf < 7; ++nf) {
      int row = nf * 16 + r15;
      s16x8 bh = frag32(buf, row, kb);
      s16x8 bl = frag32(buf + 3584, row, kb);
      f32x4 a0 = acc[0][nf], a1 = acc[1][nf];
      a0 = mfma16(l0, bh, a0); a0 = mfma16(h0, bl, a0); a0 = mfma16(h0, bh, a0);
      a1 = mfma16(l1, bh, a1); a1 = mfma16(h1, bl, a1); a1 = mfma16(h1, bh, a1);
      acc[0][nf] = a0; acc[1][nf] = a1;
    }
  };
#define WAITCF() { if (w < 2) asm volatile("s_waitcnt vmcnt(8)" ::: "memory"); \
                   else       asm volatile("s_waitcnt vmcnt(7)" ::: "memory"); }

  float4 rA[4], rB[4];
  u16 *p0 = sm, *p1 = sm + 7168, *p2 = sm + 14336;
  ALOADR(0, rA);
  stageB(p0, 0);
  for (int kp = 0; kp < 16; ++kp) {
    int k = kp * 2;
    ALOADR(k + 1, rB);
    stageB(p1, k + 1);
    WAITCF();
    __builtin_amdgcn_s_barrier();
    computeK(p0, rA, k);
    if (k + 2 < 32) {
      ALOADR(k + 2, rA);
      stageB(p2, k + 2);
      WAITCF();
    } else {
      asm volatile("s_waitcnt vmcnt(0)" ::: "memory");
    }
    __builtin_amdgcn_s_barrier();
    computeK(p1, rB, k + 1);
    u16* tmp = p0; p0 = p2; p2 = p1; p1 = tmp;
  }
  __syncthreads();

  float c2v[7];
#pragma unroll
  for (int nf = 0; nf < 7; ++nf) {
    int cc = nf * 16 + r15;
    float4 p = *(const float4*)(c2p + cc * 4);
    c2v[nf] = (p.x + p.y) + (p.z + p.w);
  }

  int cnt = 0;
#pragma unroll
  for (int mf = 0; mf < 2; ++mf)
#pragma unroll
    for (int r = 0; r < 4; ++r) {
      float bv = -INFINITY; int bi = 0x7fffffff;
#pragma unroll
      for (int nf = 0; nf < 7; ++nf) {
        float Lg = 2.f * acc[mf][nf][r] - c2v[nf];
        int cc = nf * 16 + r15;
        if (Lg > bv || (Lg == bv && cc < bi)) { bv = Lg; bi = cc; }
      }
#pragma unroll
      for (int off = 1; off < 16; off <<= 1) {
        float ov = __shfl_xor(bv, off); int oi = __shfl_xor(bi, off);
        if (ov > bv || (ov == bv && oi < bi)) { bv = ov; bi = oi; }
      }
      if (r15 == 0) {
        int qi = w * 32 + mf * 16 + (l >> 4) * 4 + r;
        cnt += (bi == qy[q0 + qi]) ? 1 : 0;
      }
    }
  if (r15 == 0) atomicAdd(corr, cnt);
#undef ALOADR
#undef WAITCF
}

// ---------------- launch ----------------

extern "C" void kernel_launch(void* const* d_in, const int* in_sizes, int n_in,
                              void* d_out, int out_size, void* d_ws, size_t ws_size,
                              hipStream_t stream) {
  const float* sx = (const float*)d_in[0];
  const int*   sy = (const int*)d_in[1];
  const float* qx = (const float*)d_in[2];
  const int*   qy = (const int*)d_in[3];

  char* base = (char*)d_ws;
  size_t o = 0;
  auto take = [&](size_t bytes) { size_t r = o; o += (bytes + 511) & ~(size_t)511; return r; };
  float* mean   = (float*)(base + take(4096));
  float* invs   = (float*)(base + take(4096));
  float* invq   = (float*)(base + take((size_t)NQ * 4));
  float* supsum = (float*)(base + take((size_t)CP * D * 4));
  float* supcnt = (float*)(base + take(512));
  float* c2pA   = (float*)(base + take(2048));
  float* c2pB   = (float*)(base + take(2048));
  float* wsump  = (float*)(base + take((size_t)(NQ / 128) * CP * 4));
  int*   corr   = (int*)(base + take(512));
  u16* cfhA = (u16*)(base + take((size_t)CP * D * 2));
  u16* cflA = (u16*)(base + take((size_t)CP * D * 2));
  u16* cfhB = (u16*)(base + take((size_t)CP * D * 2));
  u16* cflB = (u16*)(base + take((size_t)CP * D * 2));
  u8*  cf8A = (u8*)(base + take((size_t)CP * D));
  u8*  cf8B = (u8*)(base + take((size_t)CP * D));
  u8*  Wf8  = (u8*)(base + take((size_t)CP * NQ));
  float* part = (float*)(base + take((size_t)KC * CP * D * 4));
  u8*  qf8  = (u8*)(base + take((size_t)NQ * D));
  u8*  qt8  = (u8*)(base + take((size_t)NQ * D));
  size_t fast_need = o;

  if (ws_size < fast_need) {
    k_zero<<<1, 64, 0, stream>>>((int*)d_out);
    return;
  }

  k_mean<<<dim3(D / 256), 256, 0, stream>>>(sx, mean);
  k_invn<<<dim3(NS), 256, 0, stream>>>(sx, mean, invs);
  k_supsum<<<dim3(CP), 256, 0, stream>>>(sx, sy, mean, invs, supsum, supcnt);
  k_updm<1><<<dim3(CP, 4), 256, 0, stream>>>(supsum, part, wsump, supcnt,
                                             cfhA, cflA, cf8A, c2pA);
  k_qprep<<<dim3(NQ / 64), 256, 0, stream>>>(qx, mean, invq, qf8, qt8);

  u16 *chc = cfhA, *clc = cflA, *chn = cfhB, *cln = cflB;
  u8  *c8c = cf8A, *c8n = cf8B;
  float *c2c = c2pA, *c2n = c2pB;
  for (int it = 0; it < NITER; ++it) {
    k_logits8<<<dim3(NQ / 128), 256, 0, stream>>>(qf8, c8c, c2c, Wf8, wsump);
    k_wqm8<<<dim3(KC, D / 128), 256, 0, stream>>>(Wf8, qt8, part);
    k_updm<0><<<dim3(CP, 4), 256, 0, stream>>>(supsum, part, wsump, supcnt,
                                               chn, cln, c8n, c2n);
    u16* tu;
    tu = chc; chc = chn; chn = tu;
    tu = clc; clc = cln; cln = tu;
    u8* t8 = c8c; c8c = c8n; c8n = t8;
    float* tf = c2c; c2c = c2n; c2n = tf;
  }
  k_zero<<<1, 64, 0, stream>>>(corr);
  k_final<<<dim3(NQ / 128), 256, 0, stream>>>(qx, mean, invq, chc, clc, c2c,
                                              qy, corr);
  k_out<<<1, 64, 0, stream>>>(corr, (float*)d_out);
}

// Round 8
// 1587.048 us; speedup vs baseline: 2.4788x; 1.0161x over previous
//
#include <hip/hip_runtime.h>
#include <hip/hip_fp8.h>
#include <math.h>

#define NS 1000
#define NQ 131072
#define D  1024
#define C  100
#define CP 112          // padded class count (16*7)
#define BETA 5.0f
#define NITER 10
#define KC 128          // split-K chunks for W^T q
#define KROWS (NQ/KC)   // 1024 q per chunk
#define KS8 (KROWS/64)  // 16 fp8 k-steps per chunk

typedef float f32x4 __attribute__((ext_vector_type(4)));
typedef short s16x8 __attribute__((ext_vector_type(8)));
typedef long s64;
typedef s64 s64x2 __attribute__((ext_vector_type(2)));
typedef unsigned short u16;
typedef unsigned char u8;
typedef unsigned long long ull;

__device__ __forceinline__ u16 f2bf(float x) {
  union { float f; unsigned u; } v; v.f = x;
  unsigned r = v.u + 0x7fffu + ((v.u >> 16) & 1u);
  return (u16)(r >> 16);
}
__device__ __forceinline__ float bf2f(u16 h) {
  union { unsigned u; float f; } v; v.u = ((unsigned)h) << 16; return v.f;
}
__device__ __forceinline__ u8 f2fp8(float x) {
  __hip_fp8_e4m3 h(x);
  return (u8)h.__x;
}
__device__ __forceinline__ void gld16(const u16* g, u16* l) {
  __builtin_amdgcn_global_load_lds(
      (const __attribute__((address_space(1))) void*)g,
      (__attribute__((address_space(3))) void*)l, 16, 0, 0);
}
__device__ __forceinline__ void gld16b(const u8* g, u8* l) {
  __builtin_amdgcn_global_load_lds(
      (const __attribute__((address_space(1))) void*)g,
      (__attribute__((address_space(3))) void*)l, 16, 0, 0);
}
// bf16 LDS plane rows of 32 u16, 16B granule XOR-swizzled by row&3
__device__ __forceinline__ s16x8 frag32(const u16* plane, int row, int kb) {
  int s = kb ^ (row & 3);
  return *(const s16x8*)(plane + row * 32 + s * 8);
}
__device__ __forceinline__ f32x4 mfma16(s16x8 a, s16x8 b, f32x4 c) {
  return __builtin_amdgcn_mfma_f32_16x16x32_bf16(a, b, c, 0, 0, 0);
}
__device__ __forceinline__ f32x4 mfma8(s64 a, s64 b, f32x4 c) {
  return __builtin_amdgcn_mfma_f32_16x16x32_fp8_fp8(a, b, c, 0, 0, 0);
}

// ---------------- prep kernels ----------------

// mean partials over 125-row groups; grid (D/256, 8)
__global__ __launch_bounds__(256) void k_meanp(const float* __restrict__ sx,
                                               float* __restrict__ meanp) {
  int d = blockIdx.x * 256 + threadIdx.x;
  int r0 = blockIdx.y * 125;
  float a = 0.f;
  for (int r = r0; r < r0 + 125; ++r) a += sx[(size_t)r * D + d];
  meanp[(size_t)blockIdx.y * D + d] = a;
}

__global__ __launch_bounds__(256) void k_mean2(const float* __restrict__ meanp,
                                               float* __restrict__ mean) {
  int d = blockIdx.x * 256 + threadIdx.x;
  float p0 = meanp[d], p1 = meanp[D + d], p2 = meanp[2 * D + d],
        p3 = meanp[3 * D + d], p4 = meanp[4 * D + d], p5 = meanp[5 * D + d],
        p6 = meanp[6 * D + d], p7 = meanp[7 * D + d];
  mean[d] = (((p0 + p1) + (p2 + p3)) + ((p4 + p5) + (p6 + p7))) * (1.0f / (float)NS);
}

__global__ __launch_bounds__(256) void k_invn(const float* __restrict__ x,
                                              const float* __restrict__ mean,
                                              float* __restrict__ invn) {
  int r = blockIdx.x;
  int t = threadIdx.x;
  float4 v = ((const float4*)(x + (size_t)r * D))[t];
  float4 m = ((const float4*)mean)[t];
  float a = v.x - m.x, b = v.y - m.y, c = v.z - m.z, d = v.w - m.w;
  float s = a * a + b * b + c * c + d * d;
#pragma unroll
  for (int off = 1; off < 64; off <<= 1) s += __shfl_xor(s, off);
  __shared__ float ws[4];
  if ((t & 63) == 0) ws[t >> 6] = s;
  __syncthreads();
  if (t == 0) invn[r] = 1.0f / sqrtf(ws[0] + ws[1] + ws[2] + ws[3]);
}

__global__ __launch_bounds__(256) void k_supsum(const float* __restrict__ sx,
        const int* __restrict__ sy, const float* __restrict__ mean,
        const float* __restrict__ invs, float* __restrict__ supsum,
        float* __restrict__ supcnt) {
  int c = blockIdx.x;
  int t = threadIdx.x;
  float a0 = 0.f, a1 = 0.f, a2 = 0.f, a3 = 0.f;
  int cnt = 0;
  if (c < C) {
    for (int r = 0; r < NS; ++r) {
      if (sy[r] == c) {
        ++cnt;
        float inv = invs[r];
        a0 += (sx[(size_t)r * D + t      ] - mean[t      ]) * inv;
        a1 += (sx[(size_t)r * D + t + 256] - mean[t + 256]) * inv;
        a2 += (sx[(size_t)r * D + t + 512] - mean[t + 512]) * inv;
        a3 += (sx[(size_t)r * D + t + 768] - mean[t + 768]) * inv;
      }
    }
  }
  supsum[(size_t)c * D + t      ] = a0;
  supsum[(size_t)c * D + t + 256] = a1;
  supsum[(size_t)c * D + t + 512] = a2;
  supsum[(size_t)c * D + t + 768] = a3;
  if (t == 0) supcnt[c] = (float)cnt;
}

__global__ void k_zero(int* __restrict__ corr) {
  if (threadIdx.x == 0) corr[0] = 0;
}

__global__ void k_out(const int* __restrict__ corr, float* __restrict__ out) {
  if (threadIdx.x == 0) out[0] = (float)corr[0] * (1.0f / (float)NQ);
}

// fused: row norms (invq) + fp8 planes qf8 (fragment layout) + qt8 (transposed)
// grid: NQ/64 blocks x 256 threads
__global__ __launch_bounds__(256) void k_qprep(const float* __restrict__ qx,
        const float* __restrict__ mean, float* __restrict__ invq,
        u8* __restrict__ qf8, u8* __restrict__ qt8) {
  __shared__ float msh[1024];
  __shared__ float pp[64];
  __shared__ float invql[64];
  __shared__ u8 T8[64 * 68];
  int t = threadIdx.x, w = t >> 6, l = t & 63;
  int q0 = blockIdx.x * 64;
  ((float4*)msh)[t] = ((const float4*)mean)[t];
  __syncthreads();

  // phase 1: row sum-of-squares, coalesced; wave w owns rows w*16..w*16+15
#pragma unroll 1
  for (int rr = 0; rr < 16; ++rr) {
    int row = w * 16 + rr;
    const float* rp = qx + (size_t)(q0 + row) * D;
    float s = 0.f;
#pragma unroll
    for (int seg = 0; seg < 4; ++seg) {
      float4 v = *(const float4*)(rp + seg * 256 + l * 4);
      float4 m = *(const float4*)(msh + seg * 256 + l * 4);
      float a = v.x - m.x, b = v.y - m.y, c = v.z - m.z, d = v.w - m.w;
      s += a * a + b * b + c * c + d * d;
    }
#pragma unroll
    for (int off = 1; off < 64; off <<= 1) s += __shfl_xor(s, off);
    if (l == 0) pp[row] = s;
  }
  __syncthreads();
  if (t < 64) {
    float iv = 1.0f / sqrtf(pp[t]);
    invql[t] = iv;
    invq[q0 + t] = iv;
  }
  __syncthreads();

  // phase 2: convert (re-read via L2/L3), write qf8 fragments + qt8 transpose
  int r = t >> 2, c0 = (t & 3) * 16;
  float iv = invql[r];
  int h8 = (c0 >= 32) ? 1 : 0;
  int sA = (c0 & 31) >> 3;   // 0 or 2
  int lb = (r & 15) * 16 + h8 * 8;
  int tq4 = (t & 15) * 4, td4 = (t >> 4) * 4;
  for (int d0 = 0; d0 < D; d0 += 64) {
    const float* src = qx + (size_t)(q0 + r) * D + d0 + c0;
    union { u8 b[16]; ull q[2]; } F;
#pragma unroll
    for (int j = 0; j < 16; j += 4) {
      float4 v = *(const float4*)(src + j);
      float xs[4] = {v.x, v.y, v.z, v.w};
#pragma unroll
      for (int u = 0; u < 4; ++u) {
        float x = (xs[u] - msh[d0 + c0 + j + u]) * iv;
        F.b[j + u] = f2fp8(16.0f * x);
      }
    }
    // qf8 fragment plane
    size_t fb8 = (((size_t)(q0 >> 7) * 16 + (d0 >> 6)) * 8 +
                  ((q0 & 64) >> 4) + (r >> 4)) * 1024;
    *(ull*)(qf8 + fb8 + sA * 256 + lb)       = F.q[0];
    *(ull*)(qf8 + fb8 + (sA + 1) * 256 + lb) = F.q[1];
    // LDS transpose tile, pitch 68
    __syncthreads();
#pragma unroll
    for (int j = 0; j < 4; ++j)
      *(uchar4*)(T8 + r * 68 + c0 + j * 4) =
          make_uchar4(F.b[j * 4], F.b[j * 4 + 1], F.b[j * 4 + 2], F.b[j * 4 + 3]);
    __syncthreads();
    u8 a[4][4];
#pragma unroll
    for (int i = 0; i < 4; ++i)
      *(uchar4*)a[i] = *(const uchar4*)(T8 + (tq4 + i) * 68 + td4);
#pragma unroll
    for (int j = 0; j < 4; ++j)
      *(uchar4*)(qt8 + (size_t)(d0 + td4 + j) * NQ + q0 + tq4) =
          make_uchar4(a[0][j], a[1][j], a[2][j], a[3][j]);
  }
}

// centroid update; grid (CP, 4), one d-element per thread.
// c2 emitted as 4 deterministic partials c2p[c*4+by].
template<int INIT>
__global__ __launch_bounds__(256) void k_updm(const float* __restrict__ supsum,
        const u16* __restrict__ part, const float* __restrict__ wsump,
        const float* __restrict__ supcnt,
        u16* __restrict__ cfh, u16* __restrict__ cfl, u8* __restrict__ cf8,
        float* __restrict__ c2p) {
  int c = blockIdx.x, by = blockIdx.y, t = threadIdx.x;
  __shared__ float red[4];
  float den;
  if (INIT) {
    den = supcnt[c];
  } else {
    float s = 0.f;
#pragma unroll
    for (int b = 0; b < 4; ++b) s += wsump[(size_t)(t + b * 256) * CP + c];
#pragma unroll
    for (int off = 1; off < 64; off <<= 1) s += __shfl_xor(s, off);
    if ((t & 63) == 0) red[t >> 6] = s;
    __syncthreads();
    den = supcnt[c] + ((red[0] + red[1]) + (red[2] + red[3]));
    __syncthreads();
  }
  int d = by * 256 + t;
  float s = supsum[(size_t)c * D + d];
  if (!INIT) {
    float p0 = 0.f, p1 = 0.f, p2 = 0.f, p3 = 0.f;
    for (int kc = 0; kc < KC; kc += 4) {
      p0 += bf2f(part[((size_t)(kc + 0) * CP + c) * D + d]);
      p1 += bf2f(part[((size_t)(kc + 1) * CP + c) * D + d]);
      p2 += bf2f(part[((size_t)(kc + 2) * CP + c) * D + d]);
      p3 += bf2f(part[((size_t)(kc + 3) * CP + c) * D + d]);
    }
    s += 0.0009765625f * ((p0 + p1) + (p2 + p3));   // /(64*16)
  }
  float v = (c < C) ? s / den : 0.f;
  size_t a16 = (size_t)(d >> 5) * (CP * 32) + c * 32 +
               ((((d >> 3) & 3) ^ (c & 3)) * 8) + (d & 7);
  u16 h = f2bf(v);
  cfh[a16] = h;
  cfl[a16] = f2bf(v - bf2f(h));
  size_t a8 = ((size_t)(d >> 6) * CP + c) * 64 +
              ((((d >> 4) & 3) ^ (c & 3)) * 16) + (d & 15);
  cf8[a8] = f2fp8(16.0f * v);
  float ss = v * v;
#pragma unroll
  for (int off = 1; off < 64; off <<= 1) ss += __shfl_xor(ss, off);
  __syncthreads();
  if ((t & 63) == 0) red[t >> 6] = ss;
  __syncthreads();
  if (t == 0) c2p[c * 4 + by] =
      (c < C) ? ((red[0] + red[1]) + (red[2] + red[3])) : 2.5e29f;
}

// ---------------- fp8 GEMM1 (iterations): logits + softmax -> Wf8 + col sums ----------------

__global__ __launch_bounds__(256) void k_logits8(
    const u8* __restrict__ qf8, const u8* __restrict__ cf8,
    const float* __restrict__ c2p,
    u8* __restrict__ Wf8, float* __restrict__ wsump) {
  __shared__ __align__(16) u8 sm[3 * 7168];
  __shared__ float wred[4][CP];
  int t = threadIdx.x, w = t >> 6, l = t & 63;
  int qblk = blockIdx.x;
  const u8* ap0 = qf8 + (size_t)qblk * 131072 + (size_t)(w * 2) * 1024 + l * 16;
  int s_ = l >> 4, r15 = l & 15;
  int o8 = (s_ & 1) * 8;
  int go0 = s_ >> 1, go1 = 2 + (s_ >> 1);

  f32x4 acc[2][7];
#pragma unroll
  for (int mf = 0; mf < 2; ++mf)
#pragma unroll
    for (int nf = 0; nf < 7; ++nf) acc[mf][nf] = (f32x4){0.f, 0.f, 0.f, 0.f};

  auto stageB = [&](u8* buf, int kb) {
    for (int i = w; i < 7; i += 4)
      gld16b(cf8 + (size_t)kb * 7168 + i * 1024 + l * 16, buf + i * 1024);
  };
  auto computeK = [&](const u8* buf, s64x2 a0, s64x2 a1) {
#pragma unroll
    for (int nf = 0; nf < 7; ++nf) {
      int row = nf * 16 + r15;
      const u8* rp = buf + row * 64;
      int sw = row & 3;
      s64 b0 = *(const s64*)(rp + ((go0 ^ sw) << 4) + o8);
      s64 b1 = *(const s64*)(rp + ((go1 ^ sw) << 4) + o8);
      f32x4 x0 = acc[0][nf], x1 = acc[1][nf];
      x0 = mfma8(a0[0], b0, x0); x0 = mfma8(a0[1], b1, x0);
      x1 = mfma8(a1[0], b0, x1); x1 = mfma8(a1[1], b1, x1);
      acc[0][nf] = x0; acc[1][nf] = x1;
    }
  };
#define WAITC8() { if (w < 3) asm volatile("s_waitcnt vmcnt(4)" ::: "memory"); \
                   else       asm volatile("s_waitcnt vmcnt(3)" ::: "memory"); }

  s64x2 a0A, a1A, a0B, a1B;
  u8 *p0 = sm, *p1 = sm + 7168, *p2 = sm + 14336;
  a0A = *(const s64x2*)ap0; a1A = *(const s64x2*)(ap0 + 1024);
  stageB(p0, 0);
  for (int kp = 0; kp < 8; ++kp) {
    int k = kp * 2;
    { const u8* p = ap0 + (size_t)(k + 1) * 8192;
      a0B = *(const s64x2*)p; a1B = *(const s64x2*)(p + 1024); }
    stageB(p1, k + 1);
    WAITC8();
    __builtin_amdgcn_s_barrier();
    computeK(p0, a0A, a1A);
    if (k + 2 < 16) {
      const u8* p = ap0 + (size_t)(k + 2) * 8192;
      a0A = *(const s64x2*)p; a1A = *(const s64x2*)(p + 1024);
      stageB(p2, k + 2);
      WAITC8();
    } else {
      asm volatile("s_waitcnt vmcnt(0)" ::: "memory");
    }
    __builtin_amdgcn_s_barrier();
    computeK(p1, a0B, a1B);
    u8* tmp = p0; p0 = p2; p2 = p1; p1 = tmp;
  }
  __syncthreads();

  float c2v[7];
#pragma unroll
  for (int nf = 0; nf < 7; ++nf) {
    int cc = nf * 16 + r15;
    float4 p = *(const float4*)(c2p + cc * 4);
    c2v[nf] = (p.x + p.y) + (p.z + p.w);
  }

  const float LS = 2.0f / 256.0f;
  float wcol[7];
#pragma unroll
  for (int nf = 0; nf < 7; ++nf) wcol[nf] = 0.f;
  u8* Wsh8 = sm;   // [112][128] bytes, granule col-swizzle (qi>>4)^(c&7)
#pragma unroll
  for (int mf = 0; mf < 2; ++mf)
#pragma unroll
    for (int r = 0; r < 4; ++r) {
      float Lg[7], mx = -INFINITY;
#pragma unroll
      for (int nf = 0; nf < 7; ++nf) {
        Lg[nf] = LS * acc[mf][nf][r] - c2v[nf];
        mx = fmaxf(mx, Lg[nf]);
      }
#pragma unroll
      for (int off = 1; off < 16; off <<= 1) mx = fmaxf(mx, __shfl_xor(mx, off));
      float e[7], s = 0.f;
#pragma unroll
      for (int nf = 0; nf < 7; ++nf) { e[nf] = expf(BETA * (Lg[nf] - mx)); s += e[nf]; }
#pragma unroll
      for (int off = 1; off < 16; off <<= 1) s += __shfl_xor(s, off);
      float is = 1.f / s;
      int qi = w * 32 + mf * 16 + (l >> 4) * 4 + r;
#pragma unroll
      for (int nf = 0; nf < 7; ++nf) {
        float wv = e[nf] * is;
        wcol[nf] += wv;
        int cc = nf * 16 + r15;
        Wsh8[cc * 128 + (((qi >> 4) ^ (cc & 7)) << 4) + (qi & 15)] =
            f2fp8(64.0f * wv);
      }
    }
#pragma unroll
  for (int off = 16; off < 64; off <<= 1)
#pragma unroll
    for (int nf = 0; nf < 7; ++nf) wcol[nf] += __shfl_xor(wcol[nf], off);
  if (l < 16)
#pragma unroll
    for (int nf = 0; nf < 7; ++nf) wred[w][nf * 16 + l] = wcol[nf];
  __syncthreads();
  // Wf8 global: [ck][ks(16)][c][64B granule-swz g^(c&3)]
  {
    size_t wb = (size_t)(qblk >> 3) * (16 * 7168);
    int ks0 = (qblk * 2) & 15;
    for (int idx = t; idx < 896; idx += 256) {
      int c = idx >> 3, g = idx & 7;
      uint4 v = *(const uint4*)(Wsh8 + c * 128 + ((g ^ (c & 7)) << 4));
      *(uint4*)(Wf8 + wb + (size_t)(ks0 + (g >> 2)) * 7168 + c * 64 +
                (((g & 3) ^ (c & 3)) << 4)) = v;
    }
  }
  if (t < CP) wsump[(size_t)qblk * CP + t] =
      wred[0][t] + wred[1][t] + wred[2][t] + wred[3][t];
#undef WAITC8
}

// ---------------- fp8 GEMM2: part[ck] = Wf8[:,chunk] @ qt8[:,chunk]^T ----------------

__global__ __launch_bounds__(256) void k_wqm8(
    const u8* __restrict__ Wf8, const u8* __restrict__ qt8,
    u16* __restrict__ part) {
  __shared__ __align__(16) u8 sm[3][15360];   // per buf: W[112*64] | Q[128*64]
  int t = threadIdx.x, w = t >> 6, l = t & 63;
  int ck = blockIdx.x;
  int d0 = blockIdx.y * 128;
  size_t wbase = (size_t)ck * (KS8 * 7168);
  size_t qoff  = (size_t)ck * KROWS;
  int s_ = l >> 4, r15 = l & 15;
  int o8 = (s_ & 1) * 8;
  int go0 = s_ >> 1, go1 = 2 + (s_ >> 1);

  f32x4 acc[7][2];
#pragma unroll
  for (int mf = 0; mf < 7; ++mf)
#pragma unroll
    for (int nf = 0; nf < 2; ++nf) acc[mf][nf] = (f32x4){0.f, 0.f, 0.f, 0.f};

  auto stage = [&](u8* buf, int ks) {
    for (int i = w; i < 7; i += 4)
      gld16b(Wf8 + wbase + (size_t)ks * 7168 + i * 1024 + l * 16, buf + i * 1024);
#pragma unroll
    for (int i2 = w * 2; i2 < w * 2 + 2; ++i2) {
      int row = i2 * 16 + (l >> 2);
      int g = (l & 3) ^ ((l >> 2) & 3);
      gld16b(qt8 + (size_t)(d0 + row) * NQ + qoff + (size_t)ks * 64 + g * 16,
             buf + 7168 + i2 * 1024);
    }
  };
  auto computeK = [&](const u8* buf) {
    const u8* qb = buf + 7168;
    s64 bq00, bq01, bq10, bq11;
    {
      int row = w * 32 + r15;
      const u8* rp = qb + row * 64; int sw = row & 3;
      bq00 = *(const s64*)(rp + ((go0 ^ sw) << 4) + o8);
      bq01 = *(const s64*)(rp + ((go1 ^ sw) << 4) + o8);
    }
    {
      int row = w * 32 + 16 + r15;
      const u8* rp = qb + row * 64; int sw = row & 3;
      bq10 = *(const s64*)(rp + ((go0 ^ sw) << 4) + o8);
      bq11 = *(const s64*)(rp + ((go1 ^ sw) << 4) + o8);
    }
#pragma unroll
    for (int mf = 0; mf < 7; ++mf) {
      int row = mf * 16 + r15;
      const u8* rp = buf + row * 64; int sw = row & 3;
      s64 a0 = *(const s64*)(rp + ((go0 ^ sw) << 4) + o8);
      s64 a1 = *(const s64*)(rp + ((go1 ^ sw) << 4) + o8);
      f32x4 x0 = acc[mf][0], x1 = acc[mf][1];
      x0 = mfma8(a0, bq00, x0); x0 = mfma8(a1, bq01, x0);
      x1 = mfma8(a0, bq10, x1); x1 = mfma8(a1, bq11, x1);
      acc[mf][0] = x0; acc[mf][1] = x1;
    }
  };
#define WAITC4() { if (w < 3) asm volatile("s_waitcnt vmcnt(4)" ::: "memory"); \
                   else       asm volatile("s_waitcnt vmcnt(3)" ::: "memory"); }

  u8 *p0 = sm[0], *p1 = sm[1], *p2 = sm[2];
  stage(p0, 0);
  for (int kp = 0; kp < KS8 / 2; ++kp) {
    int k = kp * 2;
    stage(p1, k + 1);
    WAITC4();
    __builtin_amdgcn_s_barrier();
    computeK(p0);
    if (k + 2 < KS8) {
      stage(p2, k + 2);
      WAITC4();
    } else {
      asm volatile("s_waitcnt vmcnt(0)" ::: "memory");
    }
    __builtin_amdgcn_s_barrier();
    computeK(p1);
    u8* tmp = p0; p0 = p2; p2 = p1; p1 = tmp;
  }
#pragma unroll
  for (int mf = 0; mf < 7; ++mf)
#pragma unroll
    for (int nf = 0; nf < 2; ++nf)
#pragma unroll
      for (int r = 0; r < 4; ++r) {
        int c = mf * 16 + (l >> 4) * 4 + r;
        int dg = d0 + w * 32 + nf * 16 + r15;
        part[((size_t)ck * CP + c) * D + dg] = f2bf(acc[mf][nf][r]);
      }
#undef WAITC4
}

// ---------------- final pass: 3-term bf16 logits from raw qx + argmax ----------------

__global__ __launch_bounds__(256) void k_final(
    const float* __restrict__ qx, const float* __restrict__ mean,
    const float* __restrict__ invq,
    const u16* __restrict__ cfh, const u16* __restrict__ cfl,
    const float* __restrict__ c2p,
    const int* __restrict__ qy, int* __restrict__ corr) {
  __shared__ __align__(16) u16 sm[3 * 7168];
  __shared__ float msh[1024];
  __shared__ float ivsh[128];
  int t = threadIdx.x, w = t >> 6, l = t & 63;
  int q0 = blockIdx.x * 128;
  ((float4*)msh)[t] = ((const float4*)mean)[t];
  if (t < 32) ((float4*)ivsh)[t] = ((const float4*)(invq + q0))[t];
  __syncthreads();

  int r15 = l & 15;
  int ko = (l >> 4) * 8;
  int row0 = w * 32 + r15, row1 = row0 + 16;
  const float* a0p = qx + (size_t)(q0 + row0) * D + ko;
  const float* a1p = qx + (size_t)(q0 + row1) * D + ko;
  float iv0 = ivsh[row0], iv1 = ivsh[row1];
  int kb = l >> 4;

  f32x4 acc[2][7];
#pragma unroll
  for (int mf = 0; mf < 2; ++mf)
#pragma unroll
    for (int nf = 0; nf < 7; ++nf) acc[mf][nf] = (f32x4){0.f, 0.f, 0.f, 0.f};

#define ALOADR(ks, R) { \
    const float* p0_ = a0p + (size_t)(ks) * 32; \
    const float* p1_ = a1p + (size_t)(ks) * 32; \
    R[0] = *(const float4*)p0_; R[1] = *(const float4*)(p0_ + 4); \
    R[2] = *(const float4*)p1_; R[3] = *(const float4*)(p1_ + 4); }

  auto stageB = [&](u16* buf, int ks) {
    for (int i = w; i < 14; i += 4) {
      const u16* src = (i < 7) ? (cfh + (size_t)(ks) * 3584 + i * 512 + l * 8)
                               : (cfl + (size_t)(ks) * 3584 + (i - 7) * 512 + l * 8);
      gld16(src, buf + i * 512);
    }
  };
  auto mk = [&](const float4& u0, const float4& u1, float iv, int ks,
                s16x8& hh, s16x8& ll) {
    float xs[8] = {u0.x, u0.y, u0.z, u0.w, u1.x, u1.y, u1.z, u1.w};
#pragma unroll
    for (int u = 0; u < 8; ++u) {
      float x = (xs[u] - msh[ks * 32 + ko + u]) * iv;
      u16 h = f2bf(x);
      hh[u] = (short)h;
      ll[u] = (short)f2bf(x - bf2f(h));
    }
  };
  auto computeK = [&](const u16* buf, float4* R, int ks) {
    s16x8 h0, l0, h1, l1;
    mk(R[0], R[1], iv0, ks, h0, l0);
    mk(R[2], R[3], iv1, ks, h1, l1);
#pragma unroll
    for (int nf = 0; nf < 7; ++nf) {
      int row = nf * 16 + r15;
      s16x8 bh = frag32(buf, row, kb);
      s16x8 bl = frag32(buf + 3584, row, kb);
      f32x4 a0 = acc[0][nf], a1 = acc[1][nf];
      a0 = mfma16(l0, bh, a0); a0 = mfma16(h0, bl, a0); a0 = mfma16(h0, bh, a0);
      a1 = mfma16(l1, bh, a1); a1 = mfma16(h1, bl, a1); a1 = mfma16(h1, bh, a1);
      acc[0][nf] = a0; acc[1][nf] = a1;
    }
  };
#define WAITCF() { if (w < 2) asm volatile("s_waitcnt vmcnt(8)" ::: "memory"); \
                   else       asm volatile("s_waitcnt vmcnt(7)" ::: "memory"); }

  float4 rA[4], rB[4];
  u16 *p0 = sm, *p1 = sm + 7168, *p2 = sm + 14336;
  ALOADR(0, rA);
  stageB(p0, 0);
  for (int kp = 0; kp < 16; ++kp) {
    int k = kp * 2;
    ALOADR(k + 1, rB);
    stageB(p1, k + 1);
    WAITCF();
    __builtin_amdgcn_s_barrier();
    computeK(p0, rA, k);
    if (k + 2 < 32) {
      ALOADR(k + 2, rA);
      stageB(p2, k + 2);
      WAITCF();
    } else {
      asm volatile("s_waitcnt vmcnt(0)" ::: "memory");
    }
    __builtin_amdgcn_s_barrier();
    computeK(p1, rB, k + 1);
    u16* tmp = p0; p0 = p2; p2 = p1; p1 = tmp;
  }
  __syncthreads();

  float c2v[7];
#pragma unroll
  for (int nf = 0; nf < 7; ++nf) {
    int cc = nf * 16 + r15;
    float4 p = *(const float4*)(c2p + cc * 4);
    c2v[nf] = (p.x + p.y) + (p.z + p.w);
  }

  int cnt = 0;
#pragma unroll
  for (int mf = 0; mf < 2; ++mf)
#pragma unroll
    for (int r = 0; r < 4; ++r) {
      float bv = -INFINITY; int bi = 0x7fffffff;
#pragma unroll
      for (int nf = 0; nf < 7; ++nf) {
        float Lg = 2.f * acc[mf][nf][r] - c2v[nf];
        int cc = nf * 16 + r15;
        if (Lg > bv || (Lg == bv && cc < bi)) { bv = Lg; bi = cc; }
      }
#pragma unroll
      for (int off = 1; off < 16; off <<= 1) {
        float ov = __shfl_xor(bv, off); int oi = __shfl_xor(bi, off);
        if (ov > bv || (ov == bv && oi < bi)) { bv = ov; bi = oi; }
      }
      if (r15 == 0) {
        int qi = w * 32 + mf * 16 + (l >> 4) * 4 + r;
        cnt += (bi == qy[q0 + qi]) ? 1 : 0;
      }
    }
  if (r15 == 0) atomicAdd(corr, cnt);
#undef ALOADR
#undef WAITCF
}

// ---------------- launch ----------------

extern "C" void kernel_launch(void* const* d_in, const int* in_sizes, int n_in,
                              void* d_out, int out_size, void* d_ws, size_t ws_size,
                              hipStream_t stream) {
  const float* sx = (const float*)d_in[0];
  const int*   sy = (const int*)d_in[1];
  const float* qx = (const float*)d_in[2];
  const int*   qy = (const int*)d_in[3];

  char* base = (char*)d_ws;
  size_t o = 0;
  auto take = [&](size_t bytes) { size_t r = o; o += (bytes + 511) & ~(size_t)511; return r; };
  float* mean   = (float*)(base + take(4096));
  float* meanp  = (float*)(base + take(8 * D * 4));
  float* invs   = (float*)(base + take(4096));
  float* invq   = (float*)(base + take((size_t)NQ * 4));
  float* supsum = (float*)(base + take((size_t)CP * D * 4));
  float* supcnt = (float*)(base + take(512));
  float* c2pA   = (float*)(base + take(2048));
  float* c2pB   = (float*)(base + take(2048));
  float* wsump  = (float*)(base + take((size_t)(NQ / 128) * CP * 4));
  int*   corr   = (int*)(base + take(512));
  u16* cfhA = (u16*)(base + take((size_t)CP * D * 2));
  u16* cflA = (u16*)(base + take((size_t)CP * D * 2));
  u16* cfhB = (u16*)(base + take((size_t)CP * D * 2));
  u16* cflB = (u16*)(base + take((size_t)CP * D * 2));
  u8*  cf8A = (u8*)(base + take((size_t)CP * D));
  u8*  cf8B = (u8*)(base + take((size_t)CP * D));
  u8*  Wf8  = (u8*)(base + take((size_t)CP * NQ));
  u16* part = (u16*)(base + take((size_t)KC * CP * D * 2));
  u8*  qf8  = (u8*)(base + take((size_t)NQ * D));
  u8*  qt8  = (u8*)(base + take((size_t)NQ * D));
  size_t fast_need = o;

  if (ws_size < fast_need) {
    k_zero<<<1, 64, 0, stream>>>((int*)d_out);
    return;
  }

  k_meanp<<<dim3(D / 256, 8), 256, 0, stream>>>(sx, meanp);
  k_mean2<<<dim3(D / 256), 256, 0, stream>>>(meanp, mean);
  k_invn<<<dim3(NS), 256, 0, stream>>>(sx, mean, invs);
  k_supsum<<<dim3(CP), 256, 0, stream>>>(sx, sy, mean, invs, supsum, supcnt);
  k_updm<1><<<dim3(CP, 4), 256, 0, stream>>>(supsum, part, wsump, supcnt,
                                             cfhA, cflA, cf8A, c2pA);
  k_qprep<<<dim3(NQ / 64), 256, 0, stream>>>(qx, mean, invq, qf8, qt8);

  u16 *chc = cfhA, *clc = cflA, *chn = cfhB, *cln = cflB;
  u8  *c8c = cf8A, *c8n = cf8B;
  float *c2c = c2pA, *c2n = c2pB;
  for (int it = 0; it < NITER; ++it) {
    k_logits8<<<dim3(NQ / 128), 256, 0, stream>>>(qf8, c8c, c2c, Wf8, wsump);
    k_wqm8<<<dim3(KC, D / 128), 256, 0, stream>>>(Wf8, qt8, part);
    k_updm<0><<<dim3(CP, 4), 256, 0, stream>>>(supsum, part, wsump, supcnt,
                                               chn, cln, c8n, c2n);
    u16* tu;
    tu = chc; chc = chn; chn = tu;
    tu = clc; clc = cln; cln = tu;
    u8* t8 = c8c; c8c = c8n; c8n = t8;
    float* tf = c2c; c2c = c2n; c2n = tf;
  }
  k_zero<<<1, 64, 0, stream>>>(corr);
  k_final<<<dim3(NQ / 128), 256, 0, stream>>>(qx, mean, invq, chc, clc, c2c,
                                              qy, corr);
  k_out<<<1, 64, 0, stream>>>(corr, (float*)d_out);
}